// Round 1
// baseline (1334.145 us; speedup 1.0000x reference)
//
#include <hip/hip_runtime.h>
#include <hip/hip_bf16.h>

// ---------- types ----------
typedef __bf16 bf16x8 __attribute__((ext_vector_type(8)));
typedef unsigned short u16x8 __attribute__((ext_vector_type(8)));
typedef float f32x4 __attribute__((ext_vector_type(4)));

__device__ __forceinline__ unsigned short f2bf(float f) {
  unsigned u = __float_as_uint(f);
  u += 0x7FFF + ((u >> 16) & 1);   // RNE to bf16
  return (unsigned short)(u >> 16);
}
__device__ __forceinline__ float bf2f(unsigned short h) {
  return __uint_as_float(((unsigned)h) << 16);
}

#define T_SEQ 2048
#define HIDDEN 4096
#define NQ_HEADS 32
#define NKV_HEADS 8
#define HEAD_DIM 128
#define QKV_N 6144
#define SCALE_QK 0.08838834764831845f   /* 1/sqrt(128) */
#define SCALE_H128 0.08838834764831845f /* 1/sqrt(128) */
#define SCALE_H32 0.17677669529663687f  /* 1/sqrt(32) */

// ---------- per-row int4 fake-quant: out integer codes as bf16, plus scale ----------
__global__ __launch_bounds__(256) void quant_rows(const float* __restrict__ X,
                                                  unsigned short* __restrict__ Q,
                                                  float* __restrict__ S, int C) {
  int row = blockIdx.x;
  int tid = threadIdx.x;
  const float* x = X + (size_t)row * C;
  float amax = 0.f;
  for (int i = tid; i < C; i += 256) amax = fmaxf(amax, fabsf(x[i]));
#pragma unroll
  for (int mm = 1; mm < 64; mm <<= 1) amax = fmaxf(amax, __shfl_xor(amax, mm, 64));
  __shared__ float red[4];
  if ((tid & 63) == 0) red[tid >> 6] = amax;
  __syncthreads();
  amax = fmaxf(fmaxf(red[0], red[1]), fmaxf(red[2], red[3]));
  float s = fmaxf(amax / 7.0f, 1e-8f);  // exact div to match reference
  for (int i = tid; i < C; i += 256) {
    float v = rintf(x[i] / s);          // RNE == jnp.round
    v = fminf(fmaxf(v, -8.f), 7.f);
    Q[(size_t)row * C + i] = f2bf(v);   // exact (small int)
  }
  if (tid == 0) S[row] = s;
}

// ---------- bf16(int-code) GEMM: C[M,N] = (A[M,K] . B[N,K]^T) * sa[m]*sb[n] (+bias) ----------
// 128x128 tile, BK=32, 256 thr = 4 waves in 2x2, each wave 64x64 via 4x4 mfma_16x16x32
__global__ __launch_bounds__(256) void gemm_q4(const unsigned short* __restrict__ A,
                                               const unsigned short* __restrict__ B,
                                               const float* __restrict__ sa,
                                               const float* __restrict__ sb,
                                               const float* __restrict__ bias,
                                               float* __restrict__ C,
                                               int M, int N, int K, int hasBias) {
  __shared__ unsigned short As[128 * 40]; // padded stride 40 (2-way bank alias on reads)
  __shared__ unsigned short Bs[128 * 40];
  const int tid = threadIdx.x;
  const int lane = tid & 63;
  const int wid = tid >> 6;
  const int wm = wid >> 1, wn = wid & 1;
  const int quad = lane >> 4, l16 = lane & 15;
  const int m0 = blockIdx.y * 128, n0 = blockIdx.x * 128;

  f32x4 acc[4][4] = {};

  for (int k0 = 0; k0 < K; k0 += 32) {
#pragma unroll
    for (int r = 0; r < 2; r++) {
      int idx = tid + r * 256;      // 0..511
      int row = idx >> 2;           // 0..127
      int col = (idx & 3) * 8;      // 0,8,16,24
      *(u16x8*)&As[row * 40 + col] = *(const u16x8*)&A[(size_t)(m0 + row) * K + k0 + col];
      *(u16x8*)&Bs[row * 40 + col] = *(const u16x8*)&B[(size_t)(n0 + row) * K + k0 + col];
    }
    __syncthreads();
    bf16x8 af[4], bfr[4];
#pragma unroll
    for (int i = 0; i < 4; i++) {
      af[i]  = *(const bf16x8*)&As[(wm * 64 + i * 16 + l16) * 40 + quad * 8];
      bfr[i] = *(const bf16x8*)&Bs[(wn * 64 + i * 16 + l16) * 40 + quad * 8];
    }
#pragma unroll
    for (int i = 0; i < 4; i++)
#pragma unroll
      for (int j = 0; j < 4; j++)
        acc[i][j] = __builtin_amdgcn_mfma_f32_16x16x32_bf16(af[i], bfr[j], acc[i][j], 0, 0, 0);
    __syncthreads();
  }

#pragma unroll
  for (int i = 0; i < 4; i++) {
#pragma unroll
    for (int reg = 0; reg < 4; reg++) {
      int m = m0 + wm * 64 + i * 16 + quad * 4 + reg;
      float sm = sa[m];
#pragma unroll
      for (int j = 0; j < 4; j++) {
        int n = n0 + wn * 64 + j * 16 + l16;
        float v = acc[i][j][reg] * sm * sb[n];
        if (hasBias) v += bias[n];
        C[(size_t)m * N + n] = v;
      }
    }
  }
}

// ---------- RoPE + Hadamard-128 (q,k) and plain split (v); outputs hi/lo bf16 ----------
__global__ __launch_bounds__(256) void rope_had_kernel(const int* __restrict__ pos,
                                                       const float* __restrict__ qkv,
                                                       unsigned short* __restrict__ QH, unsigned short* __restrict__ QL,
                                                       unsigned short* __restrict__ KH, unsigned short* __restrict__ KL,
                                                       unsigned short* __restrict__ VH, unsigned short* __restrict__ VL) {
  const int w = threadIdx.x >> 6, lane = threadIdx.x & 63;
  const int vec = blockIdx.x * 4 + w;   // wave-uniform branch below
  int t, h; const float* src; unsigned short *dH, *dL; size_t o; bool doRot;
  if (vec < T_SEQ * NQ_HEADS) {
    t = vec >> 5; h = vec & 31;
    src = qkv + (size_t)t * QKV_N + h * HEAD_DIM;
    dH = QH; dL = QL; o = ((size_t)t * NQ_HEADS + h) * HEAD_DIM; doRot = true;
  } else if (vec < T_SEQ * (NQ_HEADS + NKV_HEADS)) {
    int i2 = vec - T_SEQ * NQ_HEADS; t = i2 >> 3; h = i2 & 7;
    src = qkv + (size_t)t * QKV_N + 4096 + h * HEAD_DIM;
    dH = KH; dL = KL; o = ((size_t)t * NKV_HEADS + h) * HEAD_DIM; doRot = true;
  } else {
    int i2 = vec - T_SEQ * (NQ_HEADS + NKV_HEADS); t = i2 >> 3; h = i2 & 7;
    src = qkv + (size_t)t * QKV_N + 5120 + h * HEAD_DIM;
    dH = VH; dL = VL; o = ((size_t)t * NKV_HEADS + h) * HEAD_DIM; doRot = false;
  }
  float a = src[lane], b = src[lane + 64];
  if (doRot) {
    float p = (float)pos[t];
    float fr = 1.0f / powf(10000.0f, (float)(2 * lane) * (1.0f / 128.0f));
    float ang = p * fr;
    float cs = cosf(ang), sn = sinf(ang);
    float na = a * cs - b * sn;
    float nb = b * cs + a * sn;
    // FWHT-128: stride-64 stage in-register, strides 1..32 via shuffles
    a = na + nb; b = na - nb;
#pragma unroll
    for (int mm = 1; mm <= 32; mm <<= 1) {
      float pa = __shfl_xor(a, mm, 64);
      float pb = __shfl_xor(b, mm, 64);
      bool hi = (lane & mm) != 0;
      a = hi ? (pa - a) : (a + pa);
      b = hi ? (pb - b) : (b + pb);
    }
    a *= SCALE_H128; b *= SCALE_H128;
  }
  unsigned short ah = f2bf(a), bh = f2bf(b);
  dH[o + lane] = ah;       dH[o + lane + 64] = bh;
  dL[o + lane] = f2bf(a - bf2f(ah));
  dL[o + lane + 64] = f2bf(b - bf2f(bh));
}

// ---------- flash attention, emulated-fp32 via bf16 hi/lo split MFMA ----------
// block: 4 waves; q-tile = 64 rows (16/wave), kv-tile = 32 keys
__global__ __launch_bounds__(256) void attn_kernel(const unsigned short* __restrict__ Qh, const unsigned short* __restrict__ Ql,
                                                   const unsigned short* __restrict__ Kh, const unsigned short* __restrict__ Kl,
                                                   const unsigned short* __restrict__ Vh, const unsigned short* __restrict__ Vl,
                                                   float* __restrict__ O) {
  __shared__ unsigned short smem[24064]; // 48128 B
  const int tid = threadIdx.x, lane = tid & 63, w = tid >> 6;
  const int quad = lane >> 4, l16 = lane & 15;
  const int head = blockIdx.y, qt = blockIdx.x;
  const int t0 = qt * 64;
  const int hk = head >> 2;

  unsigned short* QsH = smem;              // 64*136 (startup only)
  unsigned short* QsL = smem + 8704;
  unsigned short* KsH = smem;              // 32*136 (loop region overlays Qs)
  unsigned short* KsL = smem + 4352;
  unsigned short* VtH = smem + 8704;       // 128*40
  unsigned short* VtL = smem + 13824;
  unsigned short* Ps  = smem + 18944;      // [wave][hi/lo][16*40]

#pragma unroll
  for (int r = 0; r < 4; r++) {
    int idx = tid + r * 256;
    int row = idx >> 4, c8 = idx & 15;
    size_t g = ((size_t)(t0 + row) * NQ_HEADS + head) * HEAD_DIM + c8 * 8;
    *(u16x8*)&QsH[row * 136 + c8 * 8] = *(const u16x8*)&Qh[g];
    *(u16x8*)&QsL[row * 136 + c8 * 8] = *(const u16x8*)&Ql[g];
  }
  __syncthreads();
  bf16x8 qah[4], qal[4];
#pragma unroll
  for (int c = 0; c < 4; c++) {
    qah[c] = *(const bf16x8*)&QsH[(w * 16 + l16) * 136 + c * 32 + quad * 8];
    qal[c] = *(const bf16x8*)&QsL[(w * 16 + l16) * 136 + c * 32 + quad * 8];
  }

  f32x4 oacc[8] = {};
  float mrow[4] = {-__builtin_inff(), -__builtin_inff(), -__builtin_inff(), -__builtin_inff()};
  float lrow[4] = {0.f, 0.f, 0.f, 0.f};

  const int nt = qt * 2 + 2;
  for (int kt = 0; kt < nt; kt++) {
    __syncthreads();   // waves done reading prev K/V (and initial Qs frags)
#pragma unroll
    for (int r = 0; r < 2; r++) {
      int idx = tid + r * 256;
      int row = idx >> 4, c8 = idx & 15;
      size_t g = ((size_t)(kt * 32 + row) * NKV_HEADS + hk) * HEAD_DIM + c8 * 8;
      *(u16x8*)&KsH[row * 136 + c8 * 8] = *(const u16x8*)&Kh[g];
      *(u16x8*)&KsL[row * 136 + c8 * 8] = *(const u16x8*)&Kl[g];
      u16x8 vh = *(const u16x8*)&Vh[g];
      u16x8 vl = *(const u16x8*)&Vl[g];
#pragma unroll
      for (int e = 0; e < 8; e++) {
        VtH[(c8 * 8 + e) * 40 + row] = vh[e];
        VtL[(c8 * 8 + e) * 40 + row] = vl[e];
      }
    }
    __syncthreads();

    f32x4 sc[2] = {};
#pragma unroll
    for (int cb = 0; cb < 2; cb++) {
#pragma unroll
      for (int c = 0; c < 4; c++) {
        bf16x8 kbh = *(const bf16x8*)&KsH[(cb * 16 + l16) * 136 + c * 32 + quad * 8];
        bf16x8 kbl = *(const bf16x8*)&KsL[(cb * 16 + l16) * 136 + c * 32 + quad * 8];
        sc[cb] = __builtin_amdgcn_mfma_f32_16x16x32_bf16(qah[c], kbh, sc[cb], 0, 0, 0);
        sc[cb] = __builtin_amdgcn_mfma_f32_16x16x32_bf16(qah[c], kbl, sc[cb], 0, 0, 0);
        sc[cb] = __builtin_amdgcn_mfma_f32_16x16x32_bf16(qal[c], kbh, sc[cb], 0, 0, 0);
      }
    }

    unsigned short* myPs = Ps + w * 1280;
#pragma unroll
    for (int r = 0; r < 4; r++) {
      int qp = t0 + w * 16 + quad * 4 + r;
      float s0 = sc[0][r] * SCALE_QK;
      float s1 = sc[1][r] * SCALE_QK;
      if (kt * 32 + l16 > qp)      s0 = -__builtin_inff();
      if (kt * 32 + 16 + l16 > qp) s1 = -__builtin_inff();
      float tmax = fmaxf(s0, s1);
#pragma unroll
      for (int mm = 1; mm <= 8; mm <<= 1) tmax = fmaxf(tmax, __shfl_xor(tmax, mm, 64));
      float mnew = fmaxf(mrow[r], tmax);     // finite from kt=0 (key 0 always valid)
      float alpha = __expf(mrow[r] - mnew);
      mrow[r] = mnew;
      float p0 = __expf(s0 - mnew);
      float p1 = __expf(s1 - mnew);
      float rs = p0 + p1;
#pragma unroll
      for (int mm = 1; mm <= 8; mm <<= 1) rs += __shfl_xor(rs, mm, 64);
      lrow[r] = lrow[r] * alpha + rs;
#pragma unroll
      for (int nb = 0; nb < 8; nb++) oacc[nb][r] *= alpha;
      unsigned short h0 = f2bf(p0), h1 = f2bf(p1);
      int rr = quad * 4 + r;
      myPs[rr * 40 + l16]            = h0;
      myPs[rr * 40 + l16 + 16]       = h1;
      myPs[640 + rr * 40 + l16]      = f2bf(p0 - bf2f(h0));
      myPs[640 + rr * 40 + l16 + 16] = f2bf(p1 - bf2f(h1));
    }
    bf16x8 pfh = *(const bf16x8*)&myPs[l16 * 40 + quad * 8];
    bf16x8 pfl = *(const bf16x8*)&myPs[640 + l16 * 40 + quad * 8];
#pragma unroll
    for (int nb = 0; nb < 8; nb++) {
      bf16x8 vfh = *(const bf16x8*)&VtH[(nb * 16 + l16) * 40 + quad * 8];
      bf16x8 vfl = *(const bf16x8*)&VtL[(nb * 16 + l16) * 40 + quad * 8];
      f32x4 t = oacc[nb];
      t = __builtin_amdgcn_mfma_f32_16x16x32_bf16(pfh, vfh, t, 0, 0, 0);
      t = __builtin_amdgcn_mfma_f32_16x16x32_bf16(pfh, vfl, t, 0, 0, 0);
      t = __builtin_amdgcn_mfma_f32_16x16x32_bf16(pfl, vfh, t, 0, 0, 0);
      oacc[nb] = t;
    }
  }

#pragma unroll
  for (int r = 0; r < 4; r++) {
    int t = t0 + w * 16 + quad * 4 + r;
    float inv = 1.0f / lrow[r];
#pragma unroll
    for (int nb = 0; nb < 8; nb++)
      O[((size_t)t * NQ_HEADS + head) * HEAD_DIM + nb * 16 + l16] = oacc[nb][r] * inv;
  }
}

// ---------- head-Hadamard (32) + per-token int4 fake-quant ----------
__global__ __launch_bounds__(128) void headhad_quant(const float* __restrict__ attn,
                                                     unsigned short* __restrict__ Aq,
                                                     float* __restrict__ Sa) {
  const int t = blockIdx.x, d = threadIdx.x; // 128 threads, one d-column each
  float x[32];
#pragma unroll
  for (int h = 0; h < 32; h++) x[h] = attn[(size_t)t * 4096 + h * 128 + d];
#pragma unroll
  for (int s = 1; s < 32; s <<= 1) {
#pragma unroll
    for (int i = 0; i < 32; i++) {
      if (!(i & s)) {
        float u = x[i], v = x[i | s];
        x[i] = u + v; x[i | s] = u - v;
      }
    }
  }
  float amax = 0.f;
#pragma unroll
  for (int h = 0; h < 32; h++) { x[h] *= SCALE_H32; amax = fmaxf(amax, fabsf(x[h])); }
#pragma unroll
  for (int mm = 1; mm < 64; mm <<= 1) amax = fmaxf(amax, __shfl_xor(amax, mm, 64));
  __shared__ float red[2];
  if ((threadIdx.x & 63) == 0) red[threadIdx.x >> 6] = amax;
  __syncthreads();
  amax = fmaxf(red[0], red[1]);
  float s = fmaxf(amax / 7.0f, 1e-8f);
#pragma unroll
  for (int h = 0; h < 32; h++) {
    float q = rintf(x[h] / s);
    q = fminf(fmaxf(q, -8.f), 7.f);
    Aq[(size_t)t * 4096 + h * 128 + d] = f2bf(q);
  }
  if (threadIdx.x == 0) Sa[t] = s;
}

// ---------- launch ----------
extern "C" void kernel_launch(void* const* d_in, const int* in_sizes, int n_in,
                              void* d_out, int out_size, void* d_ws, size_t ws_size,
                              hipStream_t stream) {
  const int*   positions = (const int*)d_in[0];
  const float* hidden    = (const float*)d_in[1];
  const float* qkv_w     = (const float*)d_in[2];
  const float* qkv_b     = (const float*)d_in[3];
  const float* o_w       = (const float*)d_in[4];
  float* out = (float*)d_out;
  char* ws = (char*)d_ws;

  // region map (total ~160.1 MB)
  unsigned short* wq   = (unsigned short*)(ws + 0);          // 6144x4096 bf16 ; later owq 4096x4096
  unsigned short* xq   = (unsigned short*)(ws + 50331648);   // 2048x4096 bf16 ; later aq
  float*          qkv  = (float*)(ws + 67108864);            // 2048x6144 f32 ; later attn f32
  unsigned short* qh   = (unsigned short*)(ws + 117440512);  // 2048x32x128
  unsigned short* ql   = (unsigned short*)(ws + 134217728);
  unsigned short* kh   = (unsigned short*)(ws + 150994944);  // 2048x8x128
  unsigned short* kl   = (unsigned short*)(ws + 155189248);
  unsigned short* vh   = (unsigned short*)(ws + 159383552);
  unsigned short* vl   = (unsigned short*)(ws + 163577856);
  float* s_x  = (float*)(ws + 167772160);
  float* s_w  = (float*)(ws + 167780352);
  float* s_a  = (float*)(ws + 167804928);
  float* s_ow = (float*)(ws + 167813120);
  unsigned short* owq  = wq;                  // reuse R0 after GEMM1
  unsigned short* aq   = xq;                  // reuse R1 after GEMM1
  float* attnbuf       = qkv;                 // reuse R2 after rope

  // 1. quantize activations + qkv weights
  quant_rows<<<T_SEQ, 256, 0, stream>>>(hidden, xq, s_x, HIDDEN);
  quant_rows<<<QKV_N, 256, 0, stream>>>(qkv_w, wq, s_w, HIDDEN);
  // 2. QKV GEMM (exact int4 dot in bf16 MFMA)
  gemm_q4<<<dim3(QKV_N / 128, T_SEQ / 128), 256, 0, stream>>>(xq, wq, s_x, s_w, qkv_b,
                                                              qkv, T_SEQ, QKV_N, HIDDEN, 1);
  // 3. RoPE + Hadamard-128, hi/lo split outputs
  rope_had_kernel<<<(T_SEQ * 48) / 4, 256, 0, stream>>>(positions, qkv, qh, ql, kh, kl, vh, vl);
  // 4. quantize o_w (into reused R0)
  quant_rows<<<HIDDEN, 256, 0, stream>>>(o_w, owq, s_ow, HIDDEN);
  // 5. attention (emulated-fp32), writes attn into reused R2
  attn_kernel<<<dim3(T_SEQ / 64, NQ_HEADS), 256, 0, stream>>>(qh, ql, kh, kl, vh, vl, attnbuf);
  // 6. head-Hadamard + per-token fake-quant (into reused R1)
  headhad_quant<<<T_SEQ, 128, 0, stream>>>(attnbuf, aq, s_a);
  // 7. O-proj GEMM
  gemm_q4<<<dim3(HIDDEN / 128, T_SEQ / 128), 256, 0, stream>>>(aq, owq, s_a, s_ow, nullptr,
                                                               out, T_SEQ, HIDDEN, HIDDEN, 0);
}

// Round 2
// 742.912 us; speedup vs baseline: 1.7958x; 1.7958x over previous
//
#include <hip/hip_runtime.h>
#include <hip/hip_bf16.h>

// ---------- types ----------
typedef __bf16 bf16x8 __attribute__((ext_vector_type(8)));
typedef unsigned short u16x8 __attribute__((ext_vector_type(8)));
typedef unsigned short u16x4 __attribute__((ext_vector_type(4)));
typedef float f32x4 __attribute__((ext_vector_type(4)));

__device__ __forceinline__ unsigned short f2bf(float f) {
  unsigned u = __float_as_uint(f);
  u += 0x7FFF + ((u >> 16) & 1);   // RNE to bf16
  return (unsigned short)(u >> 16);
}
__device__ __forceinline__ float bf2f(unsigned short h) {
  return __uint_as_float(((unsigned)h) << 16);
}

#define T_SEQ 2048
#define HIDDEN 4096
#define NQ_HEADS 32
#define NKV_HEADS 8
#define HEAD_DIM 128
#define QKV_N 6144
#define SCALE_QK 0.08838834764831845f   /* 1/sqrt(128) */
#define SCALE_H128 0.08838834764831845f /* 1/sqrt(128) */
#define SCALE_H32 0.17677669529663687f  /* 1/sqrt(32) */

// ---------- per-row int4 fake-quant: out integer codes as bf16, plus scale ----------
__global__ __launch_bounds__(256) void quant_rows(const float* __restrict__ X,
                                                  unsigned short* __restrict__ Q,
                                                  float* __restrict__ S, int C) {
  int row = blockIdx.x;
  int tid = threadIdx.x;
  const float* x = X + (size_t)row * C;
  float amax = 0.f;
  for (int i = tid; i < C; i += 256) amax = fmaxf(amax, fabsf(x[i]));
#pragma unroll
  for (int mm = 1; mm < 64; mm <<= 1) amax = fmaxf(amax, __shfl_xor(amax, mm, 64));
  __shared__ float red[4];
  if ((tid & 63) == 0) red[tid >> 6] = amax;
  __syncthreads();
  amax = fmaxf(fmaxf(red[0], red[1]), fmaxf(red[2], red[3]));
  float s = fmaxf(amax / 7.0f, 1e-8f);  // exact div to match reference
  for (int i = tid; i < C; i += 256) {
    float v = rintf(x[i] / s);          // RNE == jnp.round
    v = fminf(fmaxf(v, -8.f), 7.f);
    Q[(size_t)row * C + i] = f2bf(v);   // exact (small int)
  }
  if (tid == 0) S[row] = s;
}

// ---------- bf16(int-code) GEMM: C[M,N] = (A[M,K] . B[N,K]^T) * sa[m]*sb[n] (+bias) ----------
// 128x128 tile, BK=32, 256 thr = 4 waves in 2x2, each wave 64x64 via 4x4 mfma_16x16x32
__global__ __launch_bounds__(256) void gemm_q4(const unsigned short* __restrict__ A,
                                               const unsigned short* __restrict__ B,
                                               const float* __restrict__ sa,
                                               const float* __restrict__ sb,
                                               const float* __restrict__ bias,
                                               float* __restrict__ C,
                                               int M, int N, int K, int hasBias) {
  __shared__ unsigned short As[128 * 40]; // padded stride 40 (2-way bank alias on reads)
  __shared__ unsigned short Bs[128 * 40];
  const int tid = threadIdx.x;
  const int lane = tid & 63;
  const int wid = tid >> 6;
  const int wm = wid >> 1, wn = wid & 1;
  const int quad = lane >> 4, l16 = lane & 15;
  const int m0 = blockIdx.y * 128, n0 = blockIdx.x * 128;

  f32x4 acc[4][4] = {};

  for (int k0 = 0; k0 < K; k0 += 32) {
#pragma unroll
    for (int r = 0; r < 2; r++) {
      int idx = tid + r * 256;      // 0..511
      int row = idx >> 2;           // 0..127
      int col = (idx & 3) * 8;      // 0,8,16,24
      *(u16x8*)&As[row * 40 + col] = *(const u16x8*)&A[(size_t)(m0 + row) * K + k0 + col];
      *(u16x8*)&Bs[row * 40 + col] = *(const u16x8*)&B[(size_t)(n0 + row) * K + k0 + col];
    }
    __syncthreads();
    bf16x8 af[4], bfr[4];
#pragma unroll
    for (int i = 0; i < 4; i++) {
      af[i]  = *(const bf16x8*)&As[(wm * 64 + i * 16 + l16) * 40 + quad * 8];
      bfr[i] = *(const bf16x8*)&Bs[(wn * 64 + i * 16 + l16) * 40 + quad * 8];
    }
#pragma unroll
    for (int i = 0; i < 4; i++)
#pragma unroll
      for (int j = 0; j < 4; j++)
        acc[i][j] = __builtin_amdgcn_mfma_f32_16x16x32_bf16(af[i], bfr[j], acc[i][j], 0, 0, 0);
    __syncthreads();
  }

#pragma unroll
  for (int i = 0; i < 4; i++) {
#pragma unroll
    for (int reg = 0; reg < 4; reg++) {
      int m = m0 + wm * 64 + i * 16 + quad * 4 + reg;
      float sm = sa[m];
#pragma unroll
      for (int j = 0; j < 4; j++) {
        int n = n0 + wn * 64 + j * 16 + l16;
        float v = acc[i][j][reg] * sm * sb[n];
        if (hasBias) v += bias[n];
        C[(size_t)m * N + n] = v;
      }
    }
  }
}

// ---------- RoPE + Hadamard-128 (q,k) and plain split (v); outputs hi/lo bf16 ----------
__global__ __launch_bounds__(256) void rope_had_kernel(const int* __restrict__ pos,
                                                       const float* __restrict__ qkv,
                                                       unsigned short* __restrict__ QH, unsigned short* __restrict__ QL,
                                                       unsigned short* __restrict__ KH, unsigned short* __restrict__ KL,
                                                       unsigned short* __restrict__ VH, unsigned short* __restrict__ VL) {
  const int w = threadIdx.x >> 6, lane = threadIdx.x & 63;
  const int vec = blockIdx.x * 4 + w;   // wave-uniform branch below
  int t, h; const float* src; unsigned short *dH, *dL; size_t o; bool doRot;
  if (vec < T_SEQ * NQ_HEADS) {
    t = vec >> 5; h = vec & 31;
    src = qkv + (size_t)t * QKV_N + h * HEAD_DIM;
    dH = QH; dL = QL; o = ((size_t)t * NQ_HEADS + h) * HEAD_DIM; doRot = true;
  } else if (vec < T_SEQ * (NQ_HEADS + NKV_HEADS)) {
    int i2 = vec - T_SEQ * NQ_HEADS; t = i2 >> 3; h = i2 & 7;
    src = qkv + (size_t)t * QKV_N + 4096 + h * HEAD_DIM;
    dH = KH; dL = KL; o = ((size_t)t * NKV_HEADS + h) * HEAD_DIM; doRot = true;
  } else {
    int i2 = vec - T_SEQ * (NQ_HEADS + NKV_HEADS); t = i2 >> 3; h = i2 & 7;
    src = qkv + (size_t)t * QKV_N + 5120 + h * HEAD_DIM;
    dH = VH; dL = VL; o = ((size_t)t * NKV_HEADS + h) * HEAD_DIM; doRot = false;
  }
  float a = src[lane], b = src[lane + 64];
  if (doRot) {
    float p = (float)pos[t];
    float fr = 1.0f / powf(10000.0f, (float)(2 * lane) * (1.0f / 128.0f));
    float ang = p * fr;
    float cs = cosf(ang), sn = sinf(ang);
    float na = a * cs - b * sn;
    float nb = b * cs + a * sn;
    // FWHT-128: stride-64 stage in-register, strides 1..32 via shuffles
    a = na + nb; b = na - nb;
#pragma unroll
    for (int mm = 1; mm <= 32; mm <<= 1) {
      float pa = __shfl_xor(a, mm, 64);
      float pb = __shfl_xor(b, mm, 64);
      bool hi = (lane & mm) != 0;
      a = hi ? (pa - a) : (a + pa);
      b = hi ? (pb - b) : (b + pb);
    }
    a *= SCALE_H128; b *= SCALE_H128;
  }
  unsigned short ah = f2bf(a), bh = f2bf(b);
  dH[o + lane] = ah;       dH[o + lane + 64] = bh;
  dL[o + lane] = f2bf(a - bf2f(ah));
  dL[o + lane + 64] = f2bf(b - bf2f(bh));
}

// ---------- V transpose: [t][hk][128] hi/lo -> V^T [hk][128][2048] hi/lo ----------
__global__ __launch_bounds__(256) void vtrans_kernel(const unsigned short* __restrict__ Vh,
                                                     const unsigned short* __restrict__ Vl,
                                                     unsigned short* __restrict__ VtH,
                                                     unsigned short* __restrict__ VtL) {
  __shared__ unsigned short sm[17408];  // 2 x 64x136
  unsigned short* SH = sm;
  unsigned short* SL = sm + 8704;
  const int tid = threadIdx.x;
  const int t0 = blockIdx.x * 64, h = blockIdx.y;
#pragma unroll
  for (int r = 0; r < 4; r++) {
    int G = tid + r * 256;             // 1024 granules of 8 shorts
    int row = G >> 4, g = G & 15;
    size_t src = ((size_t)(t0 + row) * NKV_HEADS + h) * HEAD_DIM + g * 8;
    *(u16x8*)&SH[row * 136 + g * 8] = *(const u16x8*)&Vh[src];
    *(u16x8*)&SL[row * 136 + g * 8] = *(const u16x8*)&Vl[src];
  }
  __syncthreads();
#pragma unroll
  for (int r = 0; r < 4; r++) {
    int G = tid + r * 256;
    int d = G >> 3, gt = G & 7;
    u16x8 a, b;
#pragma unroll
    for (int e = 0; e < 8; e++) {
      a[e] = SH[(gt * 8 + e) * 136 + d];
      b[e] = SL[(gt * 8 + e) * 136 + d];
    }
    size_t dst = ((size_t)h * HEAD_DIM + d) * T_SEQ + t0 + gt * 8;
    *(u16x8*)&VtH[dst] = a;
    *(u16x8*)&VtL[dst] = b;
  }
}

// ---------- flash attention v2: S^T orientation, emulated-fp32 bf16 hi/lo ----------
// block: 4 waves, q-tile 128 (32 rows/wave), kv-tile 32 keys, xor-swizzled LDS
__global__ __launch_bounds__(256, 2) void attn_kernel(const unsigned short* __restrict__ Qh, const unsigned short* __restrict__ Ql,
                                                      const unsigned short* __restrict__ Kh, const unsigned short* __restrict__ Kl,
                                                      const unsigned short* __restrict__ VtH, const unsigned short* __restrict__ VtL,
                                                      float* __restrict__ O) {
  __shared__ unsigned short smem[24576];   // 49152 B
  unsigned short* KsH = smem;              // 32 keys x 128 d, swizzled
  unsigned short* KsL = smem + 4096;
  unsigned short* VsH = smem + 8192;       // 128 d x 32 t, swizzled
  unsigned short* VsL = smem + 12288;
  unsigned short* Ps  = smem + 16384;      // per wave: hi[32x32], lo[32x32]

  const int tid = threadIdx.x, lane = tid & 63, w = tid >> 6;
  const int quad = lane >> 4, l16 = lane & 15;
  // balanced mapping: blocks b and b+256 get qt and 15-qt (uniform per-CU sums)
  const int tt = blockIdx.x;
  const int base = tt & 255;
  const int head = (base >> 4) | ((tt >> 8) << 4);
  const int qt = (tt < 256) ? (base & 15) : (15 - (base & 15));
  const int q0 = qt * 128;
  const int hk = head >> 2;

  // Q fragments (B-operand): lane l16 = q-row, quad*8+j = dim
  bf16x8 qbh[2][4], qbl[2][4];
#pragma unroll
  for (int nb = 0; nb < 2; nb++)
#pragma unroll
    for (int kf = 0; kf < 4; kf++) {
      size_t g = ((size_t)(q0 + w * 32 + nb * 16 + l16) * NQ_HEADS + head) * HEAD_DIM + kf * 32 + quad * 8;
      qbh[nb][kf] = *(const bf16x8*)&Qh[g];
      qbl[nb][kf] = *(const bf16x8*)&Ql[g];
    }

  f32x4 oacc[2][8] = {};
  float mrow[2] = {-__builtin_inff(), -__builtin_inff()};
  float lrow[2] = {0.f, 0.f};
  unsigned short* myP = Ps + w * 2048;
  const int wqmax = q0 + w * 32 + 31;
  const int nkt = qt * 4 + 4;

  for (int kt = 0; kt < nkt; kt++) {
    __syncthreads();
    // stage K (32x128) and V^T (128x32), hi+lo, 16B-granule xor swizzle
#pragma unroll
    for (int r = 0; r < 2; r++) {
      int G = tid + r * 256;
      {
        int row = G >> 4, g = G & 15, phys = g ^ (row & 7);
        size_t src = ((size_t)(kt * 32 + row) * NKV_HEADS + hk) * HEAD_DIM + g * 8;
        int dst = row * 128 + phys * 8;
        *(u16x8*)&KsH[dst] = *(const u16x8*)&Kh[src];
        *(u16x8*)&KsL[dst] = *(const u16x8*)&Kl[src];
      }
      {
        int d = G >> 2, g = G & 3, phys = g ^ (d & 3);
        size_t src = ((size_t)hk * HEAD_DIM + d) * T_SEQ + kt * 32 + g * 8;
        int dst = d * 32 + phys * 8;
        *(u16x8*)&VsH[dst] = *(const u16x8*)&VtH[src];
        *(u16x8*)&VsL[dst] = *(const u16x8*)&VtL[src];
      }
    }
    __syncthreads();
    if (kt * 32 > wqmax) continue;   // fully-masked for this wave

    // S^T = K . Q^T  (D[m=key][n=q]) — 3-term bf16 emulation
    f32x4 sc[2][2] = {};             // [mb(key16)][nb(q16)]
#pragma unroll
    for (int kf = 0; kf < 4; kf++) {
      bf16x8 kah[2], kal[2];
#pragma unroll
      for (int mb = 0; mb < 2; mb++) {
        int row = mb * 16 + l16;
        int phys = (kf * 4 + quad) ^ (l16 & 7);
        kah[mb] = *(const bf16x8*)&KsH[row * 128 + phys * 8];
        kal[mb] = *(const bf16x8*)&KsL[row * 128 + phys * 8];
      }
#pragma unroll
      for (int mb = 0; mb < 2; mb++)
#pragma unroll
        for (int nb = 0; nb < 2; nb++) {
          sc[mb][nb] = __builtin_amdgcn_mfma_f32_16x16x32_bf16(kah[mb], qbh[nb][kf], sc[mb][nb], 0, 0, 0);
          sc[mb][nb] = __builtin_amdgcn_mfma_f32_16x16x32_bf16(kah[mb], qbl[nb][kf], sc[mb][nb], 0, 0, 0);
          sc[mb][nb] = __builtin_amdgcn_mfma_f32_16x16x32_bf16(kal[mb], qbh[nb][kf], sc[mb][nb], 0, 0, 0);
        }
    }

    // mask + online softmax (lane l16 = q-row; reduce in-lane then across quads)
    float alpha_s[2];
#pragma unroll
    for (int nb = 0; nb < 2; nb++) {
      int qg = q0 + w * 32 + nb * 16 + l16;
#pragma unroll
      for (int mb = 0; mb < 2; mb++)
#pragma unroll
        for (int r = 0; r < 4; r++) {
          int kg = kt * 32 + mb * 16 + quad * 4 + r;
          float s = sc[mb][nb][r] * SCALE_QK;
          sc[mb][nb][r] = (kg > qg) ? -__builtin_inff() : s;
        }
      float tmax = sc[0][nb][0];
#pragma unroll
      for (int r = 1; r < 4; r++) tmax = fmaxf(tmax, sc[0][nb][r]);
#pragma unroll
      for (int r = 0; r < 4; r++) tmax = fmaxf(tmax, sc[1][nb][r]);
      tmax = fmaxf(tmax, __shfl_xor(tmax, 16, 64));
      tmax = fmaxf(tmax, __shfl_xor(tmax, 32, 64));
      float mnew = fmaxf(mrow[nb], tmax);
      float alpha = __expf(mrow[nb] - mnew);
      mrow[nb] = mnew;
      float rs = 0.f;
#pragma unroll
      for (int mb = 0; mb < 2; mb++)
#pragma unroll
        for (int r = 0; r < 4; r++) {
          float p = __expf(sc[mb][nb][r] - mnew);
          sc[mb][nb][r] = p;
          rs += p;
        }
      rs += __shfl_xor(rs, 16, 64);
      rs += __shfl_xor(rs, 32, 64);
      lrow[nb] = lrow[nb] * alpha + rs;
      alpha_s[nb] = alpha;
      // pack P hi/lo, b64 writes into per-wave region (swizzled, conflict-free)
#pragma unroll
      for (int mb = 0; mb < 2; mb++) {
        u16x4 h4, l4;
#pragma unroll
        for (int r = 0; r < 4; r++) {
          float p = sc[mb][nb][r];
          unsigned short hsh = f2bf(p);
          h4[r] = hsh;
          l4[r] = f2bf(p - bf2f(hsh));
        }
        int row = nb * 16 + l16;
        int phys = (mb * 2 + (quad >> 1)) ^ (row & 3);
        int addr = row * 32 + phys * 8 + (quad & 1) * 4;
        *(u16x4*)&myP[addr] = h4;
        *(u16x4*)&myP[1024 + addr] = l4;
      }
    }

    // rescale O by alpha (alpha lives in lane l16=q; O rows are quad*4+r)
#pragma unroll
    for (int mbq = 0; mbq < 2; mbq++)
#pragma unroll
      for (int r = 0; r < 4; r++) {
        float al = __shfl(alpha_s[mbq], quad * 4 + r, 64);
#pragma unroll
        for (int nbd = 0; nbd < 8; nbd++) oacc[mbq][nbd][r] *= al;
      }

    // PV: O[m=q][n=d] += P . V  (A=P from LDS, B=V^T from LDS)
    bf16x8 pah[2], pal[2];
#pragma unroll
    for (int mbq = 0; mbq < 2; mbq++) {
      int row = mbq * 16 + l16;
      int phys = quad ^ (row & 3);
      pah[mbq] = *(const bf16x8*)&myP[row * 32 + phys * 8];
      pal[mbq] = *(const bf16x8*)&myP[1024 + row * 32 + phys * 8];
    }
#pragma unroll
    for (int nbd = 0; nbd < 8; nbd++) {
      int d = nbd * 16 + l16;
      int phys = quad ^ (d & 3);
      bf16x8 vbh = *(const bf16x8*)&VsH[d * 32 + phys * 8];
      bf16x8 vbl = *(const bf16x8*)&VsL[d * 32 + phys * 8];
#pragma unroll
      for (int mbq = 0; mbq < 2; mbq++) {
        f32x4 t = oacc[mbq][nbd];
        t = __builtin_amdgcn_mfma_f32_16x16x32_bf16(pah[mbq], vbh, t, 0, 0, 0);
        t = __builtin_amdgcn_mfma_f32_16x16x32_bf16(pah[mbq], vbl, t, 0, 0, 0);
        t = __builtin_amdgcn_mfma_f32_16x16x32_bf16(pal[mbq], vbh, t, 0, 0, 0);
        oacc[mbq][nbd] = t;
      }
    }
  }

  // epilogue: normalize, write O [t][head][d] fp32
#pragma unroll
  for (int mbq = 0; mbq < 2; mbq++)
#pragma unroll
    for (int r = 0; r < 4; r++) {
      float lv = __shfl(lrow[mbq], quad * 4 + r, 64);
      float inv = 1.0f / lv;
      int t = q0 + w * 32 + mbq * 16 + quad * 4 + r;
#pragma unroll
      for (int nbd = 0; nbd < 8; nbd++)
        O[((size_t)t * NQ_HEADS + head) * HEAD_DIM + nbd * 16 + l16] = oacc[mbq][nbd][r] * inv;
    }
}

// ---------- head-Hadamard (32) + per-token int4 fake-quant ----------
__global__ __launch_bounds__(128) void headhad_quant(const float* __restrict__ attn,
                                                     unsigned short* __restrict__ Aq,
                                                     float* __restrict__ Sa) {
  const int t = blockIdx.x, d = threadIdx.x; // 128 threads, one d-column each
  float x[32];
#pragma unroll
  for (int h = 0; h < 32; h++) x[h] = attn[(size_t)t * 4096 + h * 128 + d];
#pragma unroll
  for (int s = 1; s < 32; s <<= 1) {
#pragma unroll
    for (int i = 0; i < 32; i++) {
      if (!(i & s)) {
        float u = x[i], v = x[i | s];
        x[i] = u + v; x[i | s] = u - v;
      }
    }
  }
  float amax = 0.f;
#pragma unroll
  for (int h = 0; h < 32; h++) { x[h] *= SCALE_H32; amax = fmaxf(amax, fabsf(x[h])); }
#pragma unroll
  for (int mm = 1; mm < 64; mm <<= 1) amax = fmaxf(amax, __shfl_xor(amax, mm, 64));
  __shared__ float red[2];
  if ((threadIdx.x & 63) == 0) red[threadIdx.x >> 6] = amax;
  __syncthreads();
  amax = fmaxf(red[0], red[1]);
  float s = fmaxf(amax / 7.0f, 1e-8f);
#pragma unroll
  for (int h = 0; h < 32; h++) {
    float q = rintf(x[h] / s);
    q = fminf(fmaxf(q, -8.f), 7.f);
    Aq[(size_t)t * 4096 + h * 128 + d] = f2bf(q);
  }
  if (threadIdx.x == 0) Sa[t] = s;
}

// ---------- launch ----------
extern "C" void kernel_launch(void* const* d_in, const int* in_sizes, int n_in,
                              void* d_out, int out_size, void* d_ws, size_t ws_size,
                              hipStream_t stream) {
  const int*   positions = (const int*)d_in[0];
  const float* hidden    = (const float*)d_in[1];
  const float* qkv_w     = (const float*)d_in[2];
  const float* qkv_b     = (const float*)d_in[3];
  const float* o_w       = (const float*)d_in[4];
  float* out = (float*)d_out;
  char* ws = (char*)d_ws;

  // region map (total ~160.1 MB)
  unsigned short* wq   = (unsigned short*)(ws + 0);          // 6144x4096 bf16 ; later owq 4096x4096
  unsigned short* xq   = (unsigned short*)(ws + 50331648);   // 2048x4096 bf16 ; later vth/vtl then aq
  float*          qkv  = (float*)(ws + 67108864);            // 2048x6144 f32 ; later attn f32
  unsigned short* qh   = (unsigned short*)(ws + 117440512);  // 2048x32x128
  unsigned short* ql   = (unsigned short*)(ws + 134217728);
  unsigned short* kh   = (unsigned short*)(ws + 150994944);  // 2048x8x128
  unsigned short* kl   = (unsigned short*)(ws + 155189248);
  unsigned short* vh   = (unsigned short*)(ws + 159383552);
  unsigned short* vl   = (unsigned short*)(ws + 163577856);
  float* s_x  = (float*)(ws + 167772160);
  float* s_w  = (float*)(ws + 167780352);
  float* s_a  = (float*)(ws + 167804928);
  float* s_ow = (float*)(ws + 167813120);
  unsigned short* owq  = wq;                                 // reuse R0 after GEMM1
  unsigned short* aq   = xq;                                 // reuse R1 after attn
  unsigned short* vth  = (unsigned short*)(ws + 50331648);   // inside R1 (xq dead after GEMM1)
  unsigned short* vtl  = (unsigned short*)(ws + 54525952);
  float* attnbuf       = qkv;                                // reuse R2 after rope

  // 1. quantize activations + qkv weights
  quant_rows<<<T_SEQ, 256, 0, stream>>>(hidden, xq, s_x, HIDDEN);
  quant_rows<<<QKV_N, 256, 0, stream>>>(qkv_w, wq, s_w, HIDDEN);
  // 2. QKV GEMM (exact int4 dot in bf16 MFMA)
  gemm_q4<<<dim3(QKV_N / 128, T_SEQ / 128), 256, 0, stream>>>(xq, wq, s_x, s_w, qkv_b,
                                                              qkv, T_SEQ, QKV_N, HIDDEN, 1);
  // 3. RoPE + Hadamard-128, hi/lo split outputs
  rope_had_kernel<<<(T_SEQ * 48) / 4, 256, 0, stream>>>(positions, qkv, qh, ql, kh, kl, vh, vl);
  // 3b. V transpose into [hk][d][t] (R1 is free now)
  vtrans_kernel<<<dim3(T_SEQ / 64, NKV_HEADS), 256, 0, stream>>>(vh, vl, vth, vtl);
  // 4. quantize o_w (into reused R0)
  quant_rows<<<HIDDEN, 256, 0, stream>>>(o_w, owq, s_ow, HIDDEN);
  // 5. attention (emulated-fp32), writes attn into reused R2
  attn_kernel<<<dim3(512), 256, 0, stream>>>(qh, ql, kh, kl, vth, vtl, attnbuf);
  // 6. head-Hadamard + per-token fake-quant (into reused R1; vth/vtl dead)
  headhad_quant<<<T_SEQ, 128, 0, stream>>>(attnbuf, aq, s_a);
  // 7. O-proj GEMM
  gemm_q4<<<dim3(HIDDEN / 128, T_SEQ / 128), 256, 0, stream>>>(aq, owq, s_a, s_ow, nullptr,
                                                               out, T_SEQ, HIDDEN, HIDDEN, 0);
}

// Round 3
// 684.905 us; speedup vs baseline: 1.9479x; 1.0847x over previous
//
#include <hip/hip_runtime.h>
#include <hip/hip_bf16.h>

// ---------- types ----------
typedef __bf16 bf16x8 __attribute__((ext_vector_type(8)));
typedef unsigned short u16x8 __attribute__((ext_vector_type(8)));
typedef unsigned short u16x4 __attribute__((ext_vector_type(4)));
typedef float f32x4 __attribute__((ext_vector_type(4)));
typedef __attribute__((address_space(3))) unsigned short lds_u16;

__device__ __forceinline__ unsigned short f2bf(float f) {
  unsigned u = __float_as_uint(f);
  u += 0x7FFF + ((u >> 16) & 1);   // RNE to bf16
  return (unsigned short)(u >> 16);
}
__device__ __forceinline__ float bf2f(unsigned short h) {
  return __uint_as_float(((unsigned)h) << 16);
}
__device__ __forceinline__ void gl_lds16(const void* g, lds_u16* l) {
  __builtin_amdgcn_global_load_lds((const __attribute__((address_space(1))) void*)g,
                                   (__attribute__((address_space(3))) void*)l, 16, 0, 0);
}

#define T_SEQ 2048
#define HIDDEN 4096
#define NQ_HEADS 32
#define NKV_HEADS 8
#define HEAD_DIM 128
#define QKV_N 6144
#define SCALE_QK 0.08838834764831845f   /* 1/sqrt(128) */
#define SCALE_H128 0.08838834764831845f /* 1/sqrt(128) */
#define SCALE_H32 0.17677669529663687f  /* 1/sqrt(32) */

// ---------- per-row int4 fake-quant (float4 loads): int codes as bf16 + scale ----------
__global__ __launch_bounds__(256) void quant_rows(const float* __restrict__ X,
                                                  unsigned short* __restrict__ Q,
                                                  float* __restrict__ S, int C) {
  int row = blockIdx.x;
  int tid = threadIdx.x;
  const f32x4* x4 = (const f32x4*)(X + (size_t)row * C);
  int C4 = C >> 2;
  float amax = 0.f;
  for (int i = tid; i < C4; i += 256) {
    f32x4 v = x4[i];
    amax = fmaxf(amax, fmaxf(fmaxf(fabsf(v[0]), fabsf(v[1])), fmaxf(fabsf(v[2]), fabsf(v[3]))));
  }
#pragma unroll
  for (int mm = 1; mm < 64; mm <<= 1) amax = fmaxf(amax, __shfl_xor(amax, mm, 64));
  __shared__ float red[4];
  if ((tid & 63) == 0) red[tid >> 6] = amax;
  __syncthreads();
  amax = fmaxf(fmaxf(red[0], red[1]), fmaxf(red[2], red[3]));
  float s = fmaxf(amax / 7.0f, 1e-8f);  // exact div to match reference
  for (int i = tid; i < C4; i += 256) {
    f32x4 v = x4[i];
    u16x4 q;
#pragma unroll
    for (int e = 0; e < 4; e++) {
      float w = rintf(v[e] / s);        // RNE == jnp.round
      w = fminf(fmaxf(w, -8.f), 7.f);
      q[e] = f2bf(w);                   // exact (small int)
    }
    *(u16x4*)&Q[(size_t)row * C + i * 4] = q;
  }
  if (tid == 0) S[row] = s;
}

// ---------- bf16(int-code) GEMM, m97-style global_load_lds staging ----------
// C[M,N] = (A[M,K] . B[N,K]^T) * sa[m]*sb[n] (+bias); 128x128 tile, BK=32
// LDS unpadded [128][32] with global-side XOR swizzle: phys granule pq,
// logical col granule = pq ^ ((row>>1)&3)  -> 2-way (free) b128 reads.
__global__ __launch_bounds__(256) void gemm_q4(const unsigned short* __restrict__ A,
                                               const unsigned short* __restrict__ B,
                                               const float* __restrict__ sa,
                                               const float* __restrict__ sb,
                                               const float* __restrict__ bias,
                                               float* __restrict__ C,
                                               int M, int N, int K, int hasBias) {
  __shared__ unsigned short As[128 * 32];
  __shared__ unsigned short Bs[128 * 32];
  lds_u16* As3 = (lds_u16*)As;
  lds_u16* Bs3 = (lds_u16*)Bs;
  const int tid = threadIdx.x;
  const int lane = tid & 63;
  const int w = tid >> 6;
  const int wm = w >> 1, wn = w & 1;
  const int quad = lane >> 4, l16 = lane & 15;
  const int m0 = blockIdx.y * 128, n0 = blockIdx.x * 128;

  f32x4 acc[4][4] = {};

  for (int k0 = 0; k0 < K; k0 += 32) {
    __syncthreads();
#pragma unroll
    for (int i = 0; i < 2; i++) {
      int u = (i * 4 + w) * 64 + lane;        // 16B-granule index, lane-contiguous
      int row = u >> 2;
      int col8 = (u & 3) ^ ((row >> 1) & 3);  // global-side swizzle
      gl_lds16(&A[(size_t)(m0 + row) * K + k0 + col8 * 8], &As3[(i * 4 + w) * 512]);
      gl_lds16(&B[(size_t)(n0 + row) * K + k0 + col8 * 8], &Bs3[(i * 4 + w) * 512]);
    }
    __syncthreads();
    bf16x8 af[4], bfr[4];
#pragma unroll
    for (int i = 0; i < 4; i++) {
      int ra = wm * 64 + i * 16 + l16;
      int rb = wn * 64 + i * 16 + l16;
      af[i]  = *(const bf16x8*)&As[ra * 32 + (quad ^ ((ra >> 1) & 3)) * 8];
      bfr[i] = *(const bf16x8*)&Bs[rb * 32 + (quad ^ ((rb >> 1) & 3)) * 8];
    }
#pragma unroll
    for (int i = 0; i < 4; i++)
#pragma unroll
      for (int j = 0; j < 4; j++)
        acc[i][j] = __builtin_amdgcn_mfma_f32_16x16x32_bf16(af[i], bfr[j], acc[i][j], 0, 0, 0);
  }

#pragma unroll
  for (int i = 0; i < 4; i++) {
#pragma unroll
    for (int reg = 0; reg < 4; reg++) {
      int m = m0 + wm * 64 + i * 16 + quad * 4 + reg;
      float sm = sa[m];
#pragma unroll
      for (int j = 0; j < 4; j++) {
        int n = n0 + wn * 64 + j * 16 + l16;
        float v = acc[i][j][reg] * sm * sb[n];
        if (hasBias) v += bias[n];
        C[(size_t)m * N + n] = v;
      }
    }
  }
}

// ---------- RoPE + Hadamard-128 (q,k) and plain split (v); outputs hi/lo bf16 ----------
__global__ __launch_bounds__(256) void rope_had_kernel(const int* __restrict__ pos,
                                                       const float* __restrict__ qkv,
                                                       unsigned short* __restrict__ QH, unsigned short* __restrict__ QL,
                                                       unsigned short* __restrict__ KH, unsigned short* __restrict__ KL,
                                                       unsigned short* __restrict__ VH, unsigned short* __restrict__ VL) {
  const int w = threadIdx.x >> 6, lane = threadIdx.x & 63;
  const int vec = blockIdx.x * 4 + w;   // wave-uniform branch below
  int t, h; const float* src; unsigned short *dH, *dL; size_t o; bool doRot;
  if (vec < T_SEQ * NQ_HEADS) {
    t = vec >> 5; h = vec & 31;
    src = qkv + (size_t)t * QKV_N + h * HEAD_DIM;
    dH = QH; dL = QL; o = ((size_t)t * NQ_HEADS + h) * HEAD_DIM; doRot = true;
  } else if (vec < T_SEQ * (NQ_HEADS + NKV_HEADS)) {
    int i2 = vec - T_SEQ * NQ_HEADS; t = i2 >> 3; h = i2 & 7;
    src = qkv + (size_t)t * QKV_N + 4096 + h * HEAD_DIM;
    dH = KH; dL = KL; o = ((size_t)t * NKV_HEADS + h) * HEAD_DIM; doRot = true;
  } else {
    int i2 = vec - T_SEQ * (NQ_HEADS + NKV_HEADS); t = i2 >> 3; h = i2 & 7;
    src = qkv + (size_t)t * QKV_N + 5120 + h * HEAD_DIM;
    dH = VH; dL = VL; o = ((size_t)t * NKV_HEADS + h) * HEAD_DIM; doRot = false;
  }
  float a = src[lane], b = src[lane + 64];
  if (doRot) {
    float p = (float)pos[t];
    float fr = 1.0f / powf(10000.0f, (float)(2 * lane) * (1.0f / 128.0f));
    float ang = p * fr;
    float cs = cosf(ang), sn = sinf(ang);
    float na = a * cs - b * sn;
    float nb = b * cs + a * sn;
    // FWHT-128: stride-64 stage in-register, strides 1..32 via shuffles
    a = na + nb; b = na - nb;
#pragma unroll
    for (int mm = 1; mm <= 32; mm <<= 1) {
      float pa = __shfl_xor(a, mm, 64);
      float pb = __shfl_xor(b, mm, 64);
      bool hi = (lane & mm) != 0;
      a = hi ? (pa - a) : (a + pa);
      b = hi ? (pb - b) : (b + pb);
    }
    a *= SCALE_H128; b *= SCALE_H128;
  }
  unsigned short ah = f2bf(a), bh = f2bf(b);
  dH[o + lane] = ah;       dH[o + lane + 64] = bh;
  dL[o + lane] = f2bf(a - bf2f(ah));
  dL[o + lane + 64] = f2bf(b - bf2f(bh));
}

// ---------- V transpose: [t][hk][128] hi/lo -> V^T [hk][128][2048] hi/lo ----------
__global__ __launch_bounds__(256) void vtrans_kernel(const unsigned short* __restrict__ Vh,
                                                     const unsigned short* __restrict__ Vl,
                                                     unsigned short* __restrict__ VtH,
                                                     unsigned short* __restrict__ VtL) {
  __shared__ unsigned short sm[17408];  // 2 x 64x136
  unsigned short* SH = sm;
  unsigned short* SL = sm + 8704;
  const int tid = threadIdx.x;
  const int t0 = blockIdx.x * 64, h = blockIdx.y;
#pragma unroll
  for (int r = 0; r < 4; r++) {
    int G = tid + r * 256;             // 1024 granules of 8 shorts
    int row = G >> 4, g = G & 15;
    size_t src = ((size_t)(t0 + row) * NKV_HEADS + h) * HEAD_DIM + g * 8;
    *(u16x8*)&SH[row * 136 + g * 8] = *(const u16x8*)&Vh[src];
    *(u16x8*)&SL[row * 136 + g * 8] = *(const u16x8*)&Vl[src];
  }
  __syncthreads();
#pragma unroll
  for (int r = 0; r < 4; r++) {
    int G = tid + r * 256;
    int d = G >> 3, gt = G & 7;
    u16x8 a, b;
#pragma unroll
    for (int e = 0; e < 8; e++) {
      a[e] = SH[(gt * 8 + e) * 136 + d];
      b[e] = SL[(gt * 8 + e) * 136 + d];
    }
    size_t dst = ((size_t)h * HEAD_DIM + d) * T_SEQ + t0 + gt * 8;
    *(u16x8*)&VtH[dst] = a;
    *(u16x8*)&VtL[dst] = b;
  }
}

// ---------- flash attention v3: register-prefetched K/V staging ----------
// block: 4 waves, q-tile 128 (32 rows/wave), kv-tile 32 keys, swizzled LDS
__global__ __launch_bounds__(256, 2) void attn_kernel(const unsigned short* __restrict__ Qh, const unsigned short* __restrict__ Ql,
                                                      const unsigned short* __restrict__ Kh, const unsigned short* __restrict__ Kl,
                                                      const unsigned short* __restrict__ VtH, const unsigned short* __restrict__ VtL,
                                                      float* __restrict__ O) {
  __shared__ unsigned short smem[24576];   // 49152 B
  unsigned short* KsH = smem;              // 32 keys x 128 d, swizzled (pg = g ^ (row&7))
  unsigned short* KsL = smem + 4096;
  unsigned short* VsH = smem + 8192;       // 128 d x 32 t, swizzled (pg = g ^ ((d>>1)&3))
  unsigned short* VsL = smem + 12288;
  unsigned short* Ps  = smem + 16384;      // per wave: hi[32x32], lo[32x32]

  const int tid = threadIdx.x, lane = tid & 63, w = tid >> 6;
  const int quad = lane >> 4, l16 = lane & 15;
  // balanced mapping: blocks b and b+256 get qt and 15-qt (uniform per-CU sums)
  const int tt = blockIdx.x;
  const int base = tt & 255;
  const int head = (base >> 4) | ((tt >> 8) << 4);
  const int qt = (tt < 256) ? (base & 15) : (15 - (base & 15));
  const int q0 = qt * 128;
  const int hk = head >> 2;

  // Q fragments (B-operand): lane l16 = q-row, quad*8+j = dim
  bf16x8 qbh[2][4], qbl[2][4];
#pragma unroll
  for (int nb = 0; nb < 2; nb++)
#pragma unroll
    for (int kf = 0; kf < 4; kf++) {
      size_t g = ((size_t)(q0 + w * 32 + nb * 16 + l16) * NQ_HEADS + head) * HEAD_DIM + kf * 32 + quad * 8;
      qbh[nb][kf] = *(const bf16x8*)&Qh[g];
      qbl[nb][kf] = *(const bf16x8*)&Ql[g];
    }

  // prefetch address precompute: this thread's two 16B granules per buffer
  const int uk0 = tid, uk1 = tid + 256;
  const int kr0 = uk0 >> 4, kg0 = (uk0 & 15) ^ (kr0 & 7);
  const int kr1 = uk1 >> 4, kg1 = (uk1 & 15) ^ (kr1 & 7);
  const size_t ko0 = (size_t)kr0 * (NKV_HEADS * HEAD_DIM) + (size_t)hk * HEAD_DIM + kg0 * 8;
  const size_t ko1 = (size_t)kr1 * (NKV_HEADS * HEAD_DIM) + (size_t)hk * HEAD_DIM + kg1 * 8;
  const int vd0 = uk0 >> 2, vg0 = (uk0 & 3) ^ ((vd0 >> 1) & 3);
  const int vd1 = uk1 >> 2, vg1 = (uk1 & 3) ^ ((vd1 >> 1) & 3);
  const size_t vo0 = ((size_t)hk * HEAD_DIM + vd0) * T_SEQ + vg0 * 8;
  const size_t vo1 = ((size_t)hk * HEAD_DIM + vd1) * T_SEQ + vg1 * 8;

  f32x4 oacc[2][8] = {};
  float mrow[2] = {-__builtin_inff(), -__builtin_inff()};
  float lrow[2] = {0.f, 0.f};
  unsigned short* myP = Ps + w * 2048;
  const int wqmax = q0 + w * 32 + 31;
  const int nkt = qt * 4 + 4;

  // prefetch tile 0
  u16x8 pkh0, pkh1, pkl0, pkl1, pvh0, pvh1, pvl0, pvl1;
  pkh0 = *(const u16x8*)&Kh[ko0];  pkh1 = *(const u16x8*)&Kh[ko1];
  pkl0 = *(const u16x8*)&Kl[ko0];  pkl1 = *(const u16x8*)&Kl[ko1];
  pvh0 = *(const u16x8*)&VtH[vo0]; pvh1 = *(const u16x8*)&VtH[vo1];
  pvl0 = *(const u16x8*)&VtL[vo0]; pvl1 = *(const u16x8*)&VtL[vo1];

  for (int kt = 0; kt < nkt; kt++) {
    __syncthreads();                       // prev compute done reading LDS
    *(u16x8*)&KsH[uk0 * 8] = pkh0;  *(u16x8*)&KsH[uk1 * 8] = pkh1;
    *(u16x8*)&KsL[uk0 * 8] = pkl0;  *(u16x8*)&KsL[uk1 * 8] = pkl1;
    *(u16x8*)&VsH[uk0 * 8] = pvh0;  *(u16x8*)&VsH[uk1 * 8] = pvh1;
    *(u16x8*)&VsL[uk0 * 8] = pvl0;  *(u16x8*)&VsL[uk1 * 8] = pvl1;
    __syncthreads();                       // tile kt visible

    // issue prefetch of tile kt+1 (clamped); completes during compute below
    {
      int ktn = (kt + 1 < nkt) ? kt + 1 : kt;
      size_t kb = (size_t)ktn * 32 * NKV_HEADS * HEAD_DIM;
      size_t vb = (size_t)ktn * 32;
      pkh0 = *(const u16x8*)&Kh[kb + ko0];  pkh1 = *(const u16x8*)&Kh[kb + ko1];
      pkl0 = *(const u16x8*)&Kl[kb + ko0];  pkl1 = *(const u16x8*)&Kl[kb + ko1];
      pvh0 = *(const u16x8*)&VtH[vb + vo0]; pvh1 = *(const u16x8*)&VtH[vb + vo1];
      pvl0 = *(const u16x8*)&VtL[vb + vo0]; pvl1 = *(const u16x8*)&VtL[vb + vo1];
    }

    if (kt * 32 > wqmax) continue;   // fully-masked for this wave (barriers done)

    // S^T = K . Q^T  (D[m=key][n=q]) — 3-term bf16 emulation
    f32x4 sc[2][2] = {};             // [mb(key16)][nb(q16)]
#pragma unroll
    for (int kf = 0; kf < 4; kf++) {
      bf16x8 kah[2], kal[2];
#pragma unroll
      for (int mb = 0; mb < 2; mb++) {
        int row = mb * 16 + l16;
        int phys = (kf * 4 + quad) ^ (l16 & 7);
        kah[mb] = *(const bf16x8*)&KsH[row * 128 + phys * 8];
        kal[mb] = *(const bf16x8*)&KsL[row * 128 + phys * 8];
      }
#pragma unroll
      for (int mb = 0; mb < 2; mb++)
#pragma unroll
        for (int nb = 0; nb < 2; nb++) {
          sc[mb][nb] = __builtin_amdgcn_mfma_f32_16x16x32_bf16(kah[mb], qbh[nb][kf], sc[mb][nb], 0, 0, 0);
          sc[mb][nb] = __builtin_amdgcn_mfma_f32_16x16x32_bf16(kah[mb], qbl[nb][kf], sc[mb][nb], 0, 0, 0);
          sc[mb][nb] = __builtin_amdgcn_mfma_f32_16x16x32_bf16(kal[mb], qbh[nb][kf], sc[mb][nb], 0, 0, 0);
        }
    }

    // mask + online softmax (lane l16 = q-row; reduce in-lane then across quads)
    float alpha_s[2];
#pragma unroll
    for (int nb = 0; nb < 2; nb++) {
      int qg = q0 + w * 32 + nb * 16 + l16;
#pragma unroll
      for (int mb = 0; mb < 2; mb++)
#pragma unroll
        for (int r = 0; r < 4; r++) {
          int kg = kt * 32 + mb * 16 + quad * 4 + r;
          float s = sc[mb][nb][r] * SCALE_QK;
          sc[mb][nb][r] = (kg > qg) ? -__builtin_inff() : s;
        }
      float tmax = sc[0][nb][0];
#pragma unroll
      for (int r = 1; r < 4; r++) tmax = fmaxf(tmax, sc[0][nb][r]);
#pragma unroll
      for (int r = 0; r < 4; r++) tmax = fmaxf(tmax, sc[1][nb][r]);
      tmax = fmaxf(tmax, __shfl_xor(tmax, 16, 64));
      tmax = fmaxf(tmax, __shfl_xor(tmax, 32, 64));
      float mnew = fmaxf(mrow[nb], tmax);
      float alpha = __expf(mrow[nb] - mnew);
      mrow[nb] = mnew;
      float rs = 0.f;
#pragma unroll
      for (int mb = 0; mb < 2; mb++)
#pragma unroll
        for (int r = 0; r < 4; r++) {
          float p = __expf(sc[mb][nb][r] - mnew);
          sc[mb][nb][r] = p;
          rs += p;
        }
      rs += __shfl_xor(rs, 16, 64);
      rs += __shfl_xor(rs, 32, 64);
      lrow[nb] = lrow[nb] * alpha + rs;
      alpha_s[nb] = alpha;
      // pack P hi/lo, b64 writes into per-wave region (swizzled, conflict-free)
#pragma unroll
      for (int mb = 0; mb < 2; mb++) {
        u16x4 h4, l4;
#pragma unroll
        for (int r = 0; r < 4; r++) {
          float p = sc[mb][nb][r];
          unsigned short hsh = f2bf(p);
          h4[r] = hsh;
          l4[r] = f2bf(p - bf2f(hsh));
        }
        int row = nb * 16 + l16;
        int phys = (mb * 2 + (quad >> 1)) ^ (row & 3);
        int addr = row * 32 + phys * 8 + (quad & 1) * 4;
        *(u16x4*)&myP[addr] = h4;
        *(u16x4*)&myP[1024 + addr] = l4;
      }
    }

    // rescale O by alpha (alpha lives in lane l16=q; O rows are quad*4+r)
#pragma unroll
    for (int mbq = 0; mbq < 2; mbq++)
#pragma unroll
      for (int r = 0; r < 4; r++) {
        float al = __shfl(alpha_s[mbq], quad * 4 + r, 64);
#pragma unroll
        for (int nbd = 0; nbd < 8; nbd++) oacc[mbq][nbd][r] *= al;
      }

    // PV: O[m=q][n=d] += P . V  (A=P from LDS, B=V^T from LDS)
    bf16x8 pah[2], pal[2];
#pragma unroll
    for (int mbq = 0; mbq < 2; mbq++) {
      int row = mbq * 16 + l16;
      int phys = quad ^ (row & 3);
      pah[mbq] = *(const bf16x8*)&myP[row * 32 + phys * 8];
      pal[mbq] = *(const bf16x8*)&myP[1024 + row * 32 + phys * 8];
    }
#pragma unroll
    for (int nbd = 0; nbd < 8; nbd++) {
      int d = nbd * 16 + l16;
      int phys = quad ^ ((d >> 1) & 3);
      bf16x8 vbh = *(const bf16x8*)&VsH[d * 32 + phys * 8];
      bf16x8 vbl = *(const bf16x8*)&VsL[d * 32 + phys * 8];
#pragma unroll
      for (int mbq = 0; mbq < 2; mbq++) {
        f32x4 t = oacc[mbq][nbd];
        t = __builtin_amdgcn_mfma_f32_16x16x32_bf16(pah[mbq], vbh, t, 0, 0, 0);
        t = __builtin_amdgcn_mfma_f32_16x16x32_bf16(pah[mbq], vbl, t, 0, 0, 0);
        t = __builtin_amdgcn_mfma_f32_16x16x32_bf16(pal[mbq], vbh, t, 0, 0, 0);
        oacc[mbq][nbd] = t;
      }
    }
  }

  // epilogue: normalize, write O [t][head][d] fp32
#pragma unroll
  for (int mbq = 0; mbq < 2; mbq++)
#pragma unroll
    for (int r = 0; r < 4; r++) {
      float lv = __shfl(lrow[mbq], quad * 4 + r, 64);
      float inv = 1.0f / lv;
      int t = q0 + w * 32 + mbq * 16 + quad * 4 + r;
#pragma unroll
      for (int nbd = 0; nbd < 8; nbd++)
        O[((size_t)t * NQ_HEADS + head) * HEAD_DIM + nbd * 16 + l16] = oacc[mbq][nbd][r] * inv;
    }
}

// ---------- head-Hadamard (32) + per-token int4 fake-quant ----------
__global__ __launch_bounds__(128) void headhad_quant(const float* __restrict__ attn,
                                                     unsigned short* __restrict__ Aq,
                                                     float* __restrict__ Sa) {
  const int t = blockIdx.x, d = threadIdx.x; // 128 threads, one d-column each
  float x[32];
#pragma unroll
  for (int h = 0; h < 32; h++) x[h] = attn[(size_t)t * 4096 + h * 128 + d];
#pragma unroll
  for (int s = 1; s < 32; s <<= 1) {
#pragma unroll
    for (int i = 0; i < 32; i++) {
      if (!(i & s)) {
        float u = x[i], v = x[i | s];
        x[i] = u + v; x[i | s] = u - v;
      }
    }
  }
  float amax = 0.f;
#pragma unroll
  for (int h = 0; h < 32; h++) { x[h] *= SCALE_H32; amax = fmaxf(amax, fabsf(x[h])); }
#pragma unroll
  for (int mm = 1; mm < 64; mm <<= 1) amax = fmaxf(amax, __shfl_xor(amax, mm, 64));
  __shared__ float red[2];
  if ((threadIdx.x & 63) == 0) red[threadIdx.x >> 6] = amax;
  __syncthreads();
  amax = fmaxf(red[0], red[1]);
  float s = fmaxf(amax / 7.0f, 1e-8f);
#pragma unroll
  for (int h = 0; h < 32; h++) {
    float q = rintf(x[h] / s);
    q = fminf(fmaxf(q, -8.f), 7.f);
    Aq[(size_t)t * 4096 + h * 128 + d] = f2bf(q);
  }
  if (threadIdx.x == 0) Sa[t] = s;
}

// ---------- launch ----------
extern "C" void kernel_launch(void* const* d_in, const int* in_sizes, int n_in,
                              void* d_out, int out_size, void* d_ws, size_t ws_size,
                              hipStream_t stream) {
  const int*   positions = (const int*)d_in[0];
  const float* hidden    = (const float*)d_in[1];
  const float* qkv_w     = (const float*)d_in[2];
  const float* qkv_b     = (const float*)d_in[3];
  const float* o_w       = (const float*)d_in[4];
  float* out = (float*)d_out;
  char* ws = (char*)d_ws;

  // region map (total ~160.1 MB)
  unsigned short* wq   = (unsigned short*)(ws + 0);          // 6144x4096 bf16 ; later owq 4096x4096
  unsigned short* xq   = (unsigned short*)(ws + 50331648);   // 2048x4096 bf16 ; later vth/vtl then aq
  float*          qkv  = (float*)(ws + 67108864);            // 2048x6144 f32 ; later attn f32
  unsigned short* qh   = (unsigned short*)(ws + 117440512);  // 2048x32x128
  unsigned short* ql   = (unsigned short*)(ws + 134217728);
  unsigned short* kh   = (unsigned short*)(ws + 150994944);  // 2048x8x128
  unsigned short* kl   = (unsigned short*)(ws + 155189248);
  unsigned short* vh   = (unsigned short*)(ws + 159383552);
  unsigned short* vl   = (unsigned short*)(ws + 163577856);
  float* s_x  = (float*)(ws + 167772160);
  float* s_w  = (float*)(ws + 167780352);
  float* s_a  = (float*)(ws + 167804928);
  float* s_ow = (float*)(ws + 167813120);
  unsigned short* owq  = wq;                                 // reuse R0 after GEMM1
  unsigned short* aq   = xq;                                 // reuse R1 after attn
  unsigned short* vth  = (unsigned short*)(ws + 50331648);   // inside R1 (xq dead after GEMM1)
  unsigned short* vtl  = (unsigned short*)(ws + 54525952);
  float* attnbuf       = qkv;                                // reuse R2 after rope

  // 1. quantize activations + qkv weights
  quant_rows<<<T_SEQ, 256, 0, stream>>>(hidden, xq, s_x, HIDDEN);
  quant_rows<<<QKV_N, 256, 0, stream>>>(qkv_w, wq, s_w, HIDDEN);
  // 2. QKV GEMM (exact int4 dot in bf16 MFMA)
  gemm_q4<<<dim3(QKV_N / 128, T_SEQ / 128), 256, 0, stream>>>(xq, wq, s_x, s_w, qkv_b,
                                                              qkv, T_SEQ, QKV_N, HIDDEN, 1);
  // 3. RoPE + Hadamard-128, hi/lo split outputs
  rope_had_kernel<<<(T_SEQ * 48) / 4, 256, 0, stream>>>(positions, qkv, qh, ql, kh, kl, vh, vl);
  // 3b. V transpose into [hk][d][t] (R1 is free now)
  vtrans_kernel<<<dim3(T_SEQ / 64, NKV_HEADS), 256, 0, stream>>>(vh, vl, vth, vtl);
  // 4. quantize o_w (into reused R0)
  quant_rows<<<HIDDEN, 256, 0, stream>>>(o_w, owq, s_ow, HIDDEN);
  // 5. attention (emulated-fp32), writes attn into reused R2
  attn_kernel<<<dim3(512), 256, 0, stream>>>(qh, ql, kh, kl, vth, vtl, attnbuf);
  // 6. head-Hadamard + per-token fake-quant (into reused R1; vth/vtl dead)
  headhad_quant<<<T_SEQ, 128, 0, stream>>>(attnbuf, aq, s_a);
  // 7. O-proj GEMM
  gemm_q4<<<dim3(HIDDEN / 128, T_SEQ / 128), 256, 0, stream>>>(aq, owq, s_a, s_ow, nullptr,
                                                               out, T_SEQ, HIDDEN, HIDDEN, 0);
}

// Round 4
// 673.042 us; speedup vs baseline: 1.9823x; 1.0176x over previous
//
#include <hip/hip_runtime.h>
#include <hip/hip_bf16.h>

// ---------- types ----------
typedef __bf16 bf16x8 __attribute__((ext_vector_type(8)));
typedef unsigned short u16x8 __attribute__((ext_vector_type(8)));
typedef unsigned short u16x4 __attribute__((ext_vector_type(4)));
typedef float f32x4 __attribute__((ext_vector_type(4)));
typedef __attribute__((address_space(3))) unsigned short lds_u16;

__device__ __forceinline__ unsigned short f2bf(float f) {
  unsigned u = __float_as_uint(f);
  u += 0x7FFF + ((u >> 16) & 1);   // RNE to bf16
  return (unsigned short)(u >> 16);
}
__device__ __forceinline__ unsigned short f2bf_trunc(float f) {
  return (unsigned short)(__float_as_uint(f) >> 16);  // RTZ: fine for hi of hi/lo split
}
__device__ __forceinline__ float bf2f(unsigned short h) {
  return __uint_as_float(((unsigned)h) << 16);
}
__device__ __forceinline__ void gl_lds16(const void* g, lds_u16* l) {
  __builtin_amdgcn_global_load_lds((const __attribute__((address_space(1))) void*)g,
                                   (__attribute__((address_space(3))) void*)l, 16, 0, 0);
}

#define T_SEQ 2048
#define HIDDEN 4096
#define NQ_HEADS 32
#define NKV_HEADS 8
#define HEAD_DIM 128
#define QKV_N 6144
#define SCALE_QK 0.08838834764831845f   /* 1/sqrt(128) */
#define SCALE_H128 0.08838834764831845f /* 1/sqrt(128) */
#define SCALE_H32 0.17677669529663687f  /* 1/sqrt(32) */

// ---------- per-row int4 fake-quant (float4 loads): int codes as bf16 + scale ----------
__global__ __launch_bounds__(256) void quant_rows(const float* __restrict__ X,
                                                  unsigned short* __restrict__ Q,
                                                  float* __restrict__ S, int C) {
  int row = blockIdx.x;
  int tid = threadIdx.x;
  const f32x4* x4 = (const f32x4*)(X + (size_t)row * C);
  int C4 = C >> 2;
  float amax = 0.f;
  for (int i = tid; i < C4; i += 256) {
    f32x4 v = x4[i];
    amax = fmaxf(amax, fmaxf(fmaxf(fabsf(v[0]), fabsf(v[1])), fmaxf(fabsf(v[2]), fabsf(v[3]))));
  }
#pragma unroll
  for (int mm = 1; mm < 64; mm <<= 1) amax = fmaxf(amax, __shfl_xor(amax, mm, 64));
  __shared__ float red[4];
  if ((tid & 63) == 0) red[tid >> 6] = amax;
  __syncthreads();
  amax = fmaxf(fmaxf(red[0], red[1]), fmaxf(red[2], red[3]));
  float s = fmaxf(amax / 7.0f, 1e-8f);  // exact div to match reference
  for (int i = tid; i < C4; i += 256) {
    f32x4 v = x4[i];
    u16x4 q;
#pragma unroll
    for (int e = 0; e < 4; e++) {
      float w = rintf(v[e] / s);        // RNE == jnp.round
      w = fminf(fmaxf(w, -8.f), 7.f);
      q[e] = f2bf(w);                   // exact (small int)
    }
    *(u16x4*)&Q[(size_t)row * C + i * 4] = q;
  }
  if (tid == 0) S[row] = s;
}

// ---------- bf16(int-code) GEMM, m97-style global_load_lds staging ----------
__global__ __launch_bounds__(256) void gemm_q4(const unsigned short* __restrict__ A,
                                               const unsigned short* __restrict__ B,
                                               const float* __restrict__ sa,
                                               const float* __restrict__ sb,
                                               const float* __restrict__ bias,
                                               float* __restrict__ C,
                                               int M, int N, int K, int hasBias) {
  __shared__ unsigned short As[128 * 32];
  __shared__ unsigned short Bs[128 * 32];
  lds_u16* As3 = (lds_u16*)As;
  lds_u16* Bs3 = (lds_u16*)Bs;
  const int tid = threadIdx.x;
  const int lane = tid & 63;
  const int w = tid >> 6;
  const int wm = w >> 1, wn = w & 1;
  const int quad = lane >> 4, l16 = lane & 15;
  const int m0 = blockIdx.y * 128, n0 = blockIdx.x * 128;

  f32x4 acc[4][4] = {};

  for (int k0 = 0; k0 < K; k0 += 32) {
    __syncthreads();
#pragma unroll
    for (int i = 0; i < 2; i++) {
      int u = (i * 4 + w) * 64 + lane;        // 16B-granule index, lane-contiguous
      int row = u >> 2;
      int col8 = (u & 3) ^ ((row >> 1) & 3);  // global-side swizzle
      gl_lds16(&A[(size_t)(m0 + row) * K + k0 + col8 * 8], &As3[(i * 4 + w) * 512]);
      gl_lds16(&B[(size_t)(n0 + row) * K + k0 + col8 * 8], &Bs3[(i * 4 + w) * 512]);
    }
    __syncthreads();
    bf16x8 af[4], bfr[4];
#pragma unroll
    for (int i = 0; i < 4; i++) {
      int ra = wm * 64 + i * 16 + l16;
      int rb = wn * 64 + i * 16 + l16;
      af[i]  = *(const bf16x8*)&As[ra * 32 + (quad ^ ((ra >> 1) & 3)) * 8];
      bfr[i] = *(const bf16x8*)&Bs[rb * 32 + (quad ^ ((rb >> 1) & 3)) * 8];
    }
#pragma unroll
    for (int i = 0; i < 4; i++)
#pragma unroll
      for (int j = 0; j < 4; j++)
        acc[i][j] = __builtin_amdgcn_mfma_f32_16x16x32_bf16(af[i], bfr[j], acc[i][j], 0, 0, 0);
  }

#pragma unroll
  for (int i = 0; i < 4; i++) {
#pragma unroll
    for (int reg = 0; reg < 4; reg++) {
      int m = m0 + wm * 64 + i * 16 + quad * 4 + reg;
      float sm = sa[m];
#pragma unroll
      for (int j = 0; j < 4; j++) {
        int n = n0 + wn * 64 + j * 16 + l16;
        float v = acc[i][j][reg] * sm * sb[n];
        if (hasBias) v += bias[n];
        C[(size_t)m * N + n] = v;
      }
    }
  }
}

// ---------- RoPE + Hadamard-128 (q,k) and plain split (v); outputs hi/lo bf16 ----------
__global__ __launch_bounds__(256) void rope_had_kernel(const int* __restrict__ pos,
                                                       const float* __restrict__ qkv,
                                                       unsigned short* __restrict__ QH, unsigned short* __restrict__ QL,
                                                       unsigned short* __restrict__ KH, unsigned short* __restrict__ KL,
                                                       unsigned short* __restrict__ VH, unsigned short* __restrict__ VL) {
  const int w = threadIdx.x >> 6, lane = threadIdx.x & 63;
  const int vec = blockIdx.x * 4 + w;   // wave-uniform branch below
  int t, h; const float* src; unsigned short *dH, *dL; size_t o; bool doRot;
  if (vec < T_SEQ * NQ_HEADS) {
    t = vec >> 5; h = vec & 31;
    src = qkv + (size_t)t * QKV_N + h * HEAD_DIM;
    dH = QH; dL = QL; o = ((size_t)t * NQ_HEADS + h) * HEAD_DIM; doRot = true;
  } else if (vec < T_SEQ * (NQ_HEADS + NKV_HEADS)) {
    int i2 = vec - T_SEQ * NQ_HEADS; t = i2 >> 3; h = i2 & 7;
    src = qkv + (size_t)t * QKV_N + 4096 + h * HEAD_DIM;
    dH = KH; dL = KL; o = ((size_t)t * NKV_HEADS + h) * HEAD_DIM; doRot = true;
  } else {
    int i2 = vec - T_SEQ * (NQ_HEADS + NKV_HEADS); t = i2 >> 3; h = i2 & 7;
    src = qkv + (size_t)t * QKV_N + 5120 + h * HEAD_DIM;
    dH = VH; dL = VL; o = ((size_t)t * NKV_HEADS + h) * HEAD_DIM; doRot = false;
  }
  float a = src[lane], b = src[lane + 64];
  if (doRot) {
    float p = (float)pos[t];
    float fr = 1.0f / powf(10000.0f, (float)(2 * lane) * (1.0f / 128.0f));
    float ang = p * fr;
    float cs = cosf(ang), sn = sinf(ang);
    float na = a * cs - b * sn;
    float nb = b * cs + a * sn;
    // FWHT-128: stride-64 stage in-register, strides 1..32 via shuffles
    a = na + nb; b = na - nb;
#pragma unroll
    for (int mm = 1; mm <= 32; mm <<= 1) {
      float pa = __shfl_xor(a, mm, 64);
      float pb = __shfl_xor(b, mm, 64);
      bool hi = (lane & mm) != 0;
      a = hi ? (pa - a) : (a + pa);
      b = hi ? (pb - b) : (b + pb);
    }
    a *= SCALE_H128; b *= SCALE_H128;
  }
  unsigned short ah = f2bf(a), bh = f2bf(b);
  dH[o + lane] = ah;       dH[o + lane + 64] = bh;
  dL[o + lane] = f2bf(a - bf2f(ah));
  dL[o + lane + 64] = f2bf(b - bf2f(bh));
}

// ---------- V transpose: [t][hk][128] hi/lo -> V^T [hk][128][2048] hi/lo ----------
__global__ __launch_bounds__(256) void vtrans_kernel(const unsigned short* __restrict__ Vh,
                                                     const unsigned short* __restrict__ Vl,
                                                     unsigned short* __restrict__ VtH,
                                                     unsigned short* __restrict__ VtL) {
  __shared__ unsigned short sm[17408];  // 2 x 64x136
  unsigned short* SH = sm;
  unsigned short* SL = sm + 8704;
  const int tid = threadIdx.x;
  const int t0 = blockIdx.x * 64, h = blockIdx.y;
#pragma unroll
  for (int r = 0; r < 4; r++) {
    int G = tid + r * 256;             // 1024 granules of 8 shorts
    int row = G >> 4, g = G & 15;
    size_t src = ((size_t)(t0 + row) * NKV_HEADS + h) * HEAD_DIM + g * 8;
    *(u16x8*)&SH[row * 136 + g * 8] = *(const u16x8*)&Vh[src];
    *(u16x8*)&SL[row * 136 + g * 8] = *(const u16x8*)&Vl[src];
  }
  __syncthreads();
#pragma unroll
  for (int r = 0; r < 4; r++) {
    int G = tid + r * 256;
    int d = G >> 3, gt = G & 7;
    u16x8 a, b;
#pragma unroll
    for (int e = 0; e < 8; e++) {
      a[e] = SH[(gt * 8 + e) * 136 + d];
      b[e] = SL[(gt * 8 + e) * 136 + d];
    }
    size_t dst = ((size_t)h * HEAD_DIM + d) * T_SEQ + t0 + gt * 8;
    *(u16x8*)&VtH[dst] = a;
    *(u16x8*)&VtL[dst] = b;
  }
}

// ---------- flash attention v4: O^T orientation, q-tile 64, 4 blocks/CU ----------
// S^T = K.Q^T (C col = q = l16); O^T = V^T.P (C col = q = l16) -> softmax state,
// alpha-rescale, and 1/l all per-lane, no shuffles. K/V staged via global_load_lds.
__global__ __launch_bounds__(256, 4) void attn_kernel(const unsigned short* __restrict__ Qh, const unsigned short* __restrict__ Ql,
                                                      const unsigned short* __restrict__ Kh, const unsigned short* __restrict__ Kl,
                                                      const unsigned short* __restrict__ VtH, const unsigned short* __restrict__ VtL,
                                                      float* __restrict__ O) {
  __shared__ unsigned short smem[20480];   // 40960 B -> 4 blocks/CU
  unsigned short* KsH = smem;              // 32 keys x 128 d   (phys g = log ^ (row&7))
  unsigned short* KsL = smem + 4096;
  unsigned short* VsH = smem + 8192;       // 128 d x 32 keys   (phys g = log ^ ((d>>1)&3))
  unsigned short* VsL = smem + 12288;
  unsigned short* Ps  = smem + 16384;      // per wave 1024: hi[16x32], lo[16x32]

  const int tid = threadIdx.x, lane = tid & 63, w = tid >> 6;
  const int quad = lane >> 4, l16 = lane & 15;
  // bijective (head,qt) mapping; per-CU qt sums constant under round-robin dispatch
  const int b = blockIdx.x;
  const int g8 = b & 255, sgrp = b >> 8;
  const int head = g8 >> 3;
  const int uu = (g8 & 7) | ((sgrp & 1) << 3);
  const int qt = (sgrp & 2) ? (31 - uu) : uu;
  const int q0 = qt * 64;
  const int hk = head >> 2;
  const int qrow = q0 + w * 16 + l16;      // this lane's q (softmax/O column)

  // Q fragments (B-operand of S^T): lane l16 = q, quad*8+j = dim
  bf16x8 qbh[4], qbl[4];
#pragma unroll
  for (int kf = 0; kf < 4; kf++) {
    size_t g = ((size_t)qrow * NQ_HEADS + head) * HEAD_DIM + kf * 32 + quad * 8;
    qbh[kf] = *(const bf16x8*)&Qh[g];
    qbl[kf] = *(const bf16x8*)&Ql[g];
  }

  // staging: thread handles granules uk0=tid, uk1=tid+256 of each buffer
  const int uk0 = tid, uk1 = tid + 256;
  const int kr0 = uk0 >> 4, kg0 = (uk0 & 15) ^ (kr0 & 7);
  const int kr1 = uk1 >> 4, kg1 = (uk1 & 15) ^ (kr1 & 7);
  const size_t ko0 = ((size_t)kr0 * NKV_HEADS + hk) * HEAD_DIM + kg0 * 8;
  const size_t ko1 = ((size_t)kr1 * NKV_HEADS + hk) * HEAD_DIM + kg1 * 8;
  const int vd0 = uk0 >> 2, vg0 = (uk0 & 3) ^ ((vd0 >> 1) & 3);
  const int vd1 = uk1 >> 2, vg1 = (uk1 & 3) ^ ((vd1 >> 1) & 3);
  const size_t vo0 = ((size_t)hk * HEAD_DIM + vd0) * T_SEQ + vg0 * 8;
  const size_t vo1 = ((size_t)hk * HEAD_DIM + vd1) * T_SEQ + vg1 * 8;
  lds_u16* dK0 = (lds_u16*)&KsH[w * 512];          // uk0 region (wave-uniform base)
  lds_u16* dK1 = (lds_u16*)&KsH[2048 + w * 512];   // uk1 region
  lds_u16* dKL0 = (lds_u16*)&KsL[w * 512];
  lds_u16* dKL1 = (lds_u16*)&KsL[2048 + w * 512];
  lds_u16* dV0 = (lds_u16*)&VsH[w * 512];
  lds_u16* dV1 = (lds_u16*)&VsH[2048 + w * 512];
  lds_u16* dVL0 = (lds_u16*)&VsL[w * 512];
  lds_u16* dVL1 = (lds_u16*)&VsL[2048 + w * 512];

  f32x4 oacc[8] = {};
  float mrow = -__builtin_inff();
  float lrow = 0.f;
  unsigned short* myP = Ps + w * 1024;
  const int swP = (l16 & 3) ^ ((l16 >> 2) & 3);
  const int wqmax = q0 + w * 16 + 15;
  const int nkt = qt * 2 + 2;

  for (int kt = 0; kt < nkt; kt++) {
    __syncthreads();                        // all waves done reading prev tile
    {
      size_t kOff = (size_t)kt * (32 * NKV_HEADS * HEAD_DIM);
      size_t vOff = (size_t)kt * 32;
      gl_lds16(&Kh[kOff + ko0], dK0);   gl_lds16(&Kh[kOff + ko1], dK1);
      gl_lds16(&Kl[kOff + ko0], dKL0);  gl_lds16(&Kl[kOff + ko1], dKL1);
      gl_lds16(&VtH[vOff + vo0], dV0);  gl_lds16(&VtH[vOff + vo1], dV1);
      gl_lds16(&VtL[vOff + vo0], dVL0); gl_lds16(&VtL[vOff + vo1], dVL1);
    }
    __syncthreads();                        // vmcnt drained -> tile visible
    if (kt * 32 > wqmax) continue;          // fully masked for this wave

    // S^T = K . Q^T  (A=K, B=Q; D col = q = l16, row = key)
    f32x4 sc[2] = {};
#pragma unroll
    for (int kf = 0; kf < 4; kf++) {
      bf16x8 kah[2], kal[2];
#pragma unroll
      for (int mb = 0; mb < 2; mb++) {
        int row = mb * 16 + l16;
        int phys = (kf * 4 + quad) ^ (l16 & 7);
        kah[mb] = *(const bf16x8*)&KsH[row * 128 + phys * 8];
        kal[mb] = *(const bf16x8*)&KsL[row * 128 + phys * 8];
      }
#pragma unroll
      for (int mb = 0; mb < 2; mb++) {
        sc[mb] = __builtin_amdgcn_mfma_f32_16x16x32_bf16(kah[mb], qbh[kf], sc[mb], 0, 0, 0);
        sc[mb] = __builtin_amdgcn_mfma_f32_16x16x32_bf16(kah[mb], qbl[kf], sc[mb], 0, 0, 0);
        sc[mb] = __builtin_amdgcn_mfma_f32_16x16x32_bf16(kal[mb], qbh[kf], sc[mb], 0, 0, 0);
      }
    }

    // scale + mask (mask only needed on the diagonal tiles; wave-uniform test)
#pragma unroll
    for (int mb = 0; mb < 2; mb++)
#pragma unroll
      for (int r = 0; r < 4; r++) sc[mb][r] *= SCALE_QK;
    if (kt * 32 + 31 > q0 + w * 16) {
#pragma unroll
      for (int mb = 0; mb < 2; mb++)
#pragma unroll
        for (int r = 0; r < 4; r++) {
          int kg = kt * 32 + mb * 16 + quad * 4 + r;
          if (kg > qrow) sc[mb][r] = -__builtin_inff();
        }
    }

    // online softmax, all per-lane (q = l16 column); reduce across quads only
    float tmax = sc[0][0];
#pragma unroll
    for (int r = 1; r < 4; r++) tmax = fmaxf(tmax, sc[0][r]);
#pragma unroll
    for (int r = 0; r < 4; r++) tmax = fmaxf(tmax, sc[1][r]);
    tmax = fmaxf(tmax, __shfl_xor(tmax, 16, 64));
    tmax = fmaxf(tmax, __shfl_xor(tmax, 32, 64));
    float mnew = fmaxf(mrow, tmax);
    float alpha = __expf(mrow - mnew);
    mrow = mnew;
    float rs = 0.f;
#pragma unroll
    for (int mb = 0; mb < 2; mb++)
#pragma unroll
      for (int r = 0; r < 4; r++) {
        float p = __expf(sc[mb][r] - mnew);
        sc[mb][r] = p;
        rs += p;
      }
    rs += __shfl_xor(rs, 16, 64);
    rs += __shfl_xor(rs, 32, 64);
    lrow = lrow * alpha + rs;
#pragma unroll
    for (int nbd = 0; nbd < 8; nbd++) oacc[nbd] *= alpha;   // per-lane, no shuffles

    // pack P hi/lo into per-wave LDS [q=l16 row][32 keys], swizzled b64 writes
#pragma unroll
    for (int mb = 0; mb < 2; mb++) {
      u16x4 h4, l4;
#pragma unroll
      for (int r = 0; r < 4; r++) {
        float p = sc[mb][r];
        unsigned short hsh = f2bf_trunc(p);
        h4[r] = hsh;
        l4[r] = f2bf(p - bf2f(hsh));
      }
      int phys = (mb * 2 + (quad >> 1)) ^ swP;
      int addr = l16 * 32 + phys * 8 + (quad & 1) * 4;
      *(u16x4*)&myP[addr] = h4;
      *(u16x4*)&myP[512 + addr] = l4;
    }

    // O^T += V^T . P  (A=V^T, B=P; D col = q = l16, row = d)
    bf16x8 pbh = *(const bf16x8*)&myP[l16 * 32 + (quad ^ swP) * 8];
    bf16x8 pbl = *(const bf16x8*)&myP[512 + l16 * 32 + (quad ^ swP) * 8];
#pragma unroll
    for (int nbd = 0; nbd < 8; nbd++) {
      int d = nbd * 16 + l16;
      int physv = quad ^ ((d >> 1) & 3);
      bf16x8 vah = *(const bf16x8*)&VsH[d * 32 + physv * 8];
      bf16x8 val = *(const bf16x8*)&VsL[d * 32 + physv * 8];
      f32x4 t = oacc[nbd];
      t = __builtin_amdgcn_mfma_f32_16x16x32_bf16(vah, pbh, t, 0, 0, 0);
      t = __builtin_amdgcn_mfma_f32_16x16x32_bf16(vah, pbl, t, 0, 0, 0);
      t = __builtin_amdgcn_mfma_f32_16x16x32_bf16(val, pbh, t, 0, 0, 0);
      oacc[nbd] = t;
    }
  }

  // epilogue: per-lane normalize; float4 stores (d = nbd*16 + quad*4 + r)
  float inv = 1.0f / lrow;
#pragma unroll
  for (int nbd = 0; nbd < 8; nbd++) {
    f32x4 o = oacc[nbd] * inv;
    *(f32x4*)&O[((size_t)qrow * NQ_HEADS + head) * HEAD_DIM + nbd * 16 + quad * 4] = o;
  }
}

// ---------- head-Hadamard (32) + per-token int4 fake-quant ----------
__global__ __launch_bounds__(128) void headhad_quant(const float* __restrict__ attn,
                                                     unsigned short* __restrict__ Aq,
                                                     float* __restrict__ Sa) {
  const int t = blockIdx.x, d = threadIdx.x; // 128 threads, one d-column each
  float x[32];
#pragma unroll
  for (int h = 0; h < 32; h++) x[h] = attn[(size_t)t * 4096 + h * 128 + d];
#pragma unroll
  for (int s = 1; s < 32; s <<= 1) {
#pragma unroll
    for (int i = 0; i < 32; i++) {
      if (!(i & s)) {
        float u = x[i], v = x[i | s];
        x[i] = u + v; x[i | s] = u - v;
      }
    }
  }
  float amax = 0.f;
#pragma unroll
  for (int h = 0; h < 32; h++) { x[h] *= SCALE_H32; amax = fmaxf(amax, fabsf(x[h])); }
#pragma unroll
  for (int mm = 1; mm < 64; mm <<= 1) amax = fmaxf(amax, __shfl_xor(amax, mm, 64));
  __shared__ float red[2];
  if ((threadIdx.x & 63) == 0) red[threadIdx.x >> 6] = amax;
  __syncthreads();
  amax = fmaxf(red[0], red[1]);
  float s = fmaxf(amax / 7.0f, 1e-8f);
#pragma unroll
  for (int h = 0; h < 32; h++) {
    float q = rintf(x[h] / s);
    q = fminf(fmaxf(q, -8.f), 7.f);
    Aq[(size_t)t * 4096 + h * 128 + d] = f2bf(q);
  }
  if (threadIdx.x == 0) Sa[t] = s;
}

// ---------- launch ----------
extern "C" void kernel_launch(void* const* d_in, const int* in_sizes, int n_in,
                              void* d_out, int out_size, void* d_ws, size_t ws_size,
                              hipStream_t stream) {
  const int*   positions = (const int*)d_in[0];
  const float* hidden    = (const float*)d_in[1];
  const float* qkv_w     = (const float*)d_in[2];
  const float* qkv_b     = (const float*)d_in[3];
  const float* o_w       = (const float*)d_in[4];
  float* out = (float*)d_out;
  char* ws = (char*)d_ws;

  // region map (total ~160.1 MB)
  unsigned short* wq   = (unsigned short*)(ws + 0);          // 6144x4096 bf16 ; later owq 4096x4096
  unsigned short* xq   = (unsigned short*)(ws + 50331648);   // 2048x4096 bf16 ; later vth/vtl then aq
  float*          qkv  = (float*)(ws + 67108864);            // 2048x6144 f32 ; later attn f32
  unsigned short* qh   = (unsigned short*)(ws + 117440512);  // 2048x32x128
  unsigned short* ql   = (unsigned short*)(ws + 134217728);
  unsigned short* kh   = (unsigned short*)(ws + 150994944);  // 2048x8x128
  unsigned short* kl   = (unsigned short*)(ws + 155189248);
  unsigned short* vh   = (unsigned short*)(ws + 159383552);
  unsigned short* vl   = (unsigned short*)(ws + 163577856);
  float* s_x  = (float*)(ws + 167772160);
  float* s_w  = (float*)(ws + 167780352);
  float* s_a  = (float*)(ws + 167804928);
  float* s_ow = (float*)(ws + 167813120);
  unsigned short* owq  = wq;                                 // reuse R0 after GEMM1
  unsigned short* aq   = xq;                                 // reuse R1 after attn
  unsigned short* vth  = (unsigned short*)(ws + 50331648);   // inside R1 (xq dead after GEMM1)
  unsigned short* vtl  = (unsigned short*)(ws + 54525952);
  float* attnbuf       = qkv;                                // reuse R2 after rope

  // 1. quantize activations + qkv weights
  quant_rows<<<T_SEQ, 256, 0, stream>>>(hidden, xq, s_x, HIDDEN);
  quant_rows<<<QKV_N, 256, 0, stream>>>(qkv_w, wq, s_w, HIDDEN);
  // 2. QKV GEMM (exact int4 dot in bf16 MFMA)
  gemm_q4<<<dim3(QKV_N / 128, T_SEQ / 128), 256, 0, stream>>>(xq, wq, s_x, s_w, qkv_b,
                                                              qkv, T_SEQ, QKV_N, HIDDEN, 1);
  // 3. RoPE + Hadamard-128, hi/lo split outputs
  rope_had_kernel<<<(T_SEQ * 48) / 4, 256, 0, stream>>>(positions, qkv, qh, ql, kh, kl, vh, vl);
  // 3b. V transpose into [hk][d][t] (R1 is free now)
  vtrans_kernel<<<dim3(T_SEQ / 64, NKV_HEADS), 256, 0, stream>>>(vh, vl, vth, vtl);
  // 4. quantize o_w (into reused R0)
  quant_rows<<<HIDDEN, 256, 0, stream>>>(o_w, owq, s_ow, HIDDEN);
  // 5. attention (emulated-fp32), writes attn into reused R2
  attn_kernel<<<dim3(1024), 256, 0, stream>>>(qh, ql, kh, kl, vth, vtl, attnbuf);
  // 6. head-Hadamard + per-token fake-quant (into reused R1; vth/vtl dead)
  headhad_quant<<<T_SEQ, 128, 0, stream>>>(attnbuf, aq, s_a);
  // 7. O-proj GEMM
  gemm_q4<<<dim3(HIDDEN / 128, T_SEQ / 128), 256, 0, stream>>>(aq, owq, s_a, s_ow, nullptr,
                                                               out, T_SEQ, HIDDEN, HIDDEN, 0);
}